// Round 3
// baseline (7223.321 us; speedup 1.0000x reference)
//
#include <hip/hip_runtime.h>
#include <hip/hip_bf16.h>

#define NB   2048          // B
#define KN   20            // neighbors per row
#define DF   128           // D (= T)
#define DQ   256           // D + T
#define DKI  384           // D + T + D
#define NROWS1 (NB + NB*KN) // 43008 layer-1 rows

#define KIN_ST 388         // padded LDS stride for k_in

// Static device scratch for layer-1 outputs. Fully written by the layer-1
// dispatch before the layer-2 dispatch reads it on every call.
__device__ float g_out1[NROWS1 * DF];

template<int LAYER>
__global__ __launch_bounds__(256)
void tgn_row_kernel(
    const float* __restrict__ nf,
    const float* __restrict__ ef,
    const float* __restrict__ mem,
    const float* __restrict__ tsv,
    const float* __restrict__ et_src,
    const float* __restrict__ et_nbr,
    const float* __restrict__ tw,
    const float* __restrict__ tb,
    const float* __restrict__ Wq, const float* __restrict__ bq,
    const float* __restrict__ Wk, const float* __restrict__ bk,
    const float* __restrict__ Wv, const float* __restrict__ bv,
    const float* __restrict__ Wo, const float* __restrict__ bo,
    const float* __restrict__ fc1w, const float* __restrict__ fc1b,
    const float* __restrict__ fc2w, const float* __restrict__ fc2b,
    const int* __restrict__ srcn,
    const int* __restrict__ nbrs_src,
    const int* __restrict__ eidx_src,
    const int* __restrict__ nbrs_nbr,
    const int* __restrict__ eidx_nbr,
    float* __restrict__ outf)   // final output (layer 2 only) -- FLOAT32
{
  const int r   = blockIdx.x;
  const int tid = threadIdx.x;
  const int lane = tid & 63;
  const int wid  = tid >> 6;

  __shared__ float sf[DF];          // src features
  __shared__ float cte[DF];         // cos(tb) = src time encoding
  __shared__ float kin[KN][KIN_ST]; // [neigh | ete | efeat] per neighbor
  __shared__ float oatt[DQ];        // attention output (pre-Wo)
  __shared__ float oo[DQ];          // after Wo (zeroed if all-masked)
  __shared__ float h1[DF];          // relu(fc1)
  __shared__ float part[4][KN];     // per-wave score partials
  __shared__ float attnw[2][KN];    // softmax weights
  __shared__ int   nid[KN];
  __shared__ float dts[KN];
  __shared__ int   eidx_sh[KN];
  __shared__ unsigned int mbits;

  const float* wq  = Wq   + LAYER*DQ*DQ;
  const float* wk  = Wk   + LAYER*DKI*DQ;
  const float* wv  = Wv   + LAYER*DKI*DQ;
  const float* wo  = Wo   + LAYER*DQ*DQ;
  const float* f1w = fc1w + LAYER*(DQ+DF)*DF;
  const float* f2w = fc2w + LAYER*DF*DF;
  const float* bqv = bq   + LAYER*DQ;
  const float* bkv = bk   + LAYER*DQ;
  const float* bvv = bv   + LAYER*DQ;
  const float* bov = bo   + LAYER*DQ;
  const float* f1b = fc1b + LAYER*DF;
  const float* f2b = fc2b + LAYER*DF;

  // ---- per-row metadata ----
  if (tid < KN) {
    int j = tid;
    if (LAYER == 0) {
      if (r < NB) {
        nid[j]     = nbrs_src[r*KN + j];
        eidx_sh[j] = eidx_src[r*KN + j];
        dts[j]     = tsv[r] - et_src[r*KN + j];
      } else {
        int rr = r - NB;
        nid[j]     = nbrs_nbr[rr*KN + j];
        eidx_sh[j] = eidx_nbr[rr*KN + j];
        dts[j]     = tsv[rr / KN] - et_nbr[rr*KN + j];
      }
    } else {
      nid[j]     = nbrs_src[r*KN + j];
      eidx_sh[j] = eidx_src[r*KN + j];
      dts[j]     = tsv[r] - et_src[r*KN + j];
    }
  }
  __syncthreads();

  if (tid == 0) {
    unsigned int mb = 0;
    for (int j = 0; j < KN; ++j) mb |= (nid[j] == 0 ? 1u : 0u) << j;
    mbits = mb;
  }

  // src features + cos(tb)
  if (tid < DF) {
    if (LAYER == 0) {
      int node = (r < NB) ? srcn[r] : nbrs_src[r - NB];
      sf[tid] = mem[node*DF + tid] + nf[node*DF + tid];
    } else {
      sf[tid] = g_out1[r*DF + tid];
    }
    cte[tid] = cosf(tb[tid]);
  }

  // build k_in = [neigh_feat | time_enc | edge_feat]
  for (int idx = tid; idx < KN*DF; idx += 256) {
    int j = idx >> 7, d = idx & 127;
    if (LAYER == 0) {
      int nb = nid[j];
      kin[j][d] = mem[nb*DF + d] + nf[nb*DF + d];
    } else {
      kin[j][d] = g_out1[(NB + r*KN + j)*DF + d];
    }
    kin[j][DF + d]   = cosf(dts[j]*tw[d] + tb[d]);
    kin[j][2*DF + d] = ef[eidx_sh[j]*DF + d];
  }
  __syncthreads();

  // ---- q projection: thread tid owns output column tid ----
  float qreg = bqv[tid];
  for (int c = 0; c < DF; ++c)  qreg += sf[c]  * wq[c*DQ + tid];
  for (int c = 0; c < DF; ++c)  qreg += cte[c] * wq[(DF + c)*DQ + tid];

  // ---- k and v projections: acc[m] per neighbor, column tid ----
  float ack[KN], acv[KN];
  #pragma unroll
  for (int m = 0; m < KN; ++m) { ack[m] = bkv[tid]; acv[m] = bvv[tid]; }
  for (int c = 0; c < DKI; c += 4) {
    float w0k = wk[(c+0)*DQ + tid];
    float w1k = wk[(c+1)*DQ + tid];
    float w2k = wk[(c+2)*DQ + tid];
    float w3k = wk[(c+3)*DQ + tid];
    float w0v = wv[(c+0)*DQ + tid];
    float w1v = wv[(c+1)*DQ + tid];
    float w2v = wv[(c+2)*DQ + tid];
    float w3v = wv[(c+3)*DQ + tid];
    #pragma unroll
    for (int m = 0; m < KN; ++m) {
      const float4 kx = *(const float4*)&kin[m][c];
      ack[m] += kx.x*w0k + kx.y*w1k + kx.z*w2k + kx.w*w3k;
      acv[m] += kx.x*w0v + kx.y*w1v + kx.z*w2v + kx.w*w3v;
    }
  }

  // ---- scores: s[h][m] = sum_d q[h,d]*k[m,h,d]; d-sum = reduce over the
  // 128 threads of head h (2 waves); butterfly within wave, pair via LDS ----
  #pragma unroll
  for (int m = 0; m < KN; ++m) {
    float p = qreg * ack[m];
    p += __shfl_xor(p, 1);
    p += __shfl_xor(p, 2);
    p += __shfl_xor(p, 4);
    p += __shfl_xor(p, 8);
    p += __shfl_xor(p, 16);
    p += __shfl_xor(p, 32);
    if (lane == 0) part[wid][m] = p;
  }
  __syncthreads();

  // ---- masked softmax over K=20 (2 threads, one per head) ----
  if (tid < 2) {
    const int h = tid;
    float s[KN];
    #pragma unroll
    for (int m = 0; m < KN; ++m) {
      float v = (part[2*h][m] + part[2*h + 1][m]) * 0.08838834764831845f;
      if ((mbits >> m) & 1u) v = -1e9f;
      s[m] = v;
    }
    float mx = -3.0e38f;
    #pragma unroll
    for (int m = 0; m < KN; ++m) mx = fmaxf(mx, s[m]);
    float sum = 0.f;
    #pragma unroll
    for (int m = 0; m < KN; ++m) { s[m] = expf(s[m] - mx); sum += s[m]; }
    float inv = 1.f / sum;
    #pragma unroll
    for (int m = 0; m < KN; ++m) attnw[h][m] = s[m] * inv;
  }
  __syncthreads();

  // ---- PV: thread-local (thread tid holds v[m][tid]) ----
  {
    const int h = tid >> 7;
    float acc = 0.f;
    #pragma unroll
    for (int m = 0; m < KN; ++m) acc += attnw[h][m] * acv[m];
    oatt[tid] = acc;
  }
  __syncthreads();

  // ---- output projection Wo (+ zero if fully masked) ----
  {
    float acc = bov[tid];
    for (int c = 0; c < DQ; ++c) acc += oatt[c] * wo[c*DQ + tid];
    if (mbits == 0xFFFFFu) acc = 0.f;
    oo[tid] = acc;
  }
  __syncthreads();

  // ---- merge MLP: h1 = relu([oo | sf] @ fc1 + b) ----
  if (tid < DF) {
    float acc = f1b[tid];
    for (int c = 0; c < DQ; ++c) acc += oo[c] * f1w[c*DF + tid];
    for (int c = 0; c < DF; ++c) acc += sf[c] * f1w[(DQ + c)*DF + tid];
    h1[tid] = fmaxf(acc, 0.f);
  }
  __syncthreads();

  // ---- out = h1 @ fc2 + b ----
  if (tid < DF) {
    float acc = f2b[tid];
    for (int c = 0; c < DF; ++c) acc += h1[c] * f2w[c*DF + tid];
    if (LAYER == 0) g_out1[r*DF + tid] = acc;
    else            outf[r*DF + tid] = acc;   // f32 store (d_out is float*)
  }
}

extern "C" void kernel_launch(void* const* d_in, const int* in_sizes, int n_in,
                              void* d_out, int out_size, void* d_ws, size_t ws_size,
                              hipStream_t stream) {
  (void)in_sizes; (void)n_in; (void)out_size; (void)ws_size; (void)d_ws;
  const float* nf   = (const float*)d_in[0];
  const float* ef   = (const float*)d_in[1];
  const float* mem  = (const float*)d_in[2];
  const float* tsv  = (const float*)d_in[3];
  const float* ets  = (const float*)d_in[4];
  const float* etn  = (const float*)d_in[5];
  const float* tw   = (const float*)d_in[6];
  const float* tb   = (const float*)d_in[7];
  const float* Wq   = (const float*)d_in[8];
  const float* bq   = (const float*)d_in[9];
  const float* Wk   = (const float*)d_in[10];
  const float* bk   = (const float*)d_in[11];
  const float* Wv   = (const float*)d_in[12];
  const float* bv   = (const float*)d_in[13];
  const float* Wo   = (const float*)d_in[14];
  const float* bo   = (const float*)d_in[15];
  const float* f1w  = (const float*)d_in[16];
  const float* f1b  = (const float*)d_in[17];
  const float* f2w  = (const float*)d_in[18];
  const float* f2b  = (const float*)d_in[19];
  const int* srcn   = (const int*)d_in[20];
  const int* nbs    = (const int*)d_in[21];
  const int* eis    = (const int*)d_in[22];
  const int* nbn    = (const int*)d_in[23];
  const int* ein    = (const int*)d_in[24];

  float* out = (float*)d_out;

  hipLaunchKernelGGL((tgn_row_kernel<0>), dim3(NROWS1), dim3(256), 0, stream,
      nf, ef, mem, tsv, ets, etn, tw, tb, Wq, bq, Wk, bk, Wv, bv, Wo, bo,
      f1w, f1b, f2w, f2b, srcn, nbs, eis, nbn, ein, (float*)nullptr);
  hipLaunchKernelGGL((tgn_row_kernel<1>), dim3(NB), dim3(256), 0, stream,
      nf, ef, mem, tsv, ets, etn, tw, tb, Wq, bq, Wk, bk, Wv, bv, Wo, bo,
      f1w, f1b, f2w, f2b, srcn, nbs, eis, nbn, ein, out);
}

// Round 4
// 2696.633 us; speedup vs baseline: 2.6786x; 2.6786x over previous
//
#include <hip/hip_runtime.h>
#include <hip/hip_bf16.h>

#define NB    2048
#define KN    20
#define DF    128
#define DQ    256
#define DKI   384          // k_in width
#define NR1   43008        // layer-1 rows (2048 src + 40960 neighbors)
#define M0    860160       // NR1*KN edge rows (layer-1 GEMM M)
#define M1    40960        // NB*KN (layer-2 GEMM M)
#define KG    48           // DKI/8 k-groups
#define NOUT  512          // k(256) | v(256)

typedef short s16x8 __attribute__((ext_vector_type(8)));
typedef float f32x4 __attribute__((ext_vector_type(4)));

// ---- static device scratch (round-2 established this works) ----
__device__ __hip_bfloat16 g_A0[(size_t)M0 * DKI];     // 660 MB, tiled layout
__device__ __hip_bfloat16 g_C0[(size_t)M0 * NOUT];    // 880 MB, row-major
__device__ __hip_bfloat16 g_A1[(size_t)M1 * DKI];
__device__ __hip_bfloat16 g_C1[(size_t)M1 * NOUT];
__device__ __hip_bfloat16 g_Bt[2 * 32 * KG * 16 * 8]; // weights, tiled
__device__ float g_out1[NR1 * DF];                    // layer-1 outputs

__device__ __forceinline__ short f2bf(float v) {
  union { __hip_bfloat16 h; short s; } u; u.h = __float2bfloat16(v); return u.s;
}

// ============ weight conversion: [Wk|Wv] f32 -> bf16 tiled ============
// B_t[L][nt][kg][16 col][8 k]; value B[k][c] = c<256 ? Wk[L][k][c] : Wv[L][k][c-256]
__global__ __launch_bounds__(256)
void k_wconv(const float* __restrict__ Wk, const float* __restrict__ Wv) {
  int slot = blockIdx.x * 256 + threadIdx.x;   // 2*32*48*16 = 49152 slots
  int cl = slot & 15;
  int t1 = slot >> 4;
  int kg = t1 % KG;
  int t2 = t1 / KG;          // L*32 + nt
  int nt = t2 & 31;
  int L  = t2 >> 5;
  int c  = nt * 16 + cl;
  const float* src; int cc;
  if (c < 256) { src = Wk + (size_t)L * DKI * DQ; cc = c; }
  else         { src = Wv + (size_t)L * DKI * DQ; cc = c - 256; }
  s16x8 o;
  #pragma unroll
  for (int e = 0; e < 8; ++e) o[e] = f2bf(src[(size_t)(kg * 8 + e) * 256 + cc]);
  *(s16x8*)(g_Bt + (size_t)slot * 8) = o;
}

// ============ gather/encode: build A in tiled bf16 layout ============
// A_t[mt][kg][16 row][8 k]; edge row m = r*KN + j
template<int L>
__global__ __launch_bounds__(256)
void k_gather(const float* __restrict__ nf, const float* __restrict__ ef,
              const float* __restrict__ mem, const float* __restrict__ tsv,
              const float* __restrict__ ets, const float* __restrict__ etn,
              const float* __restrict__ tw,  const float* __restrict__ tb,
              const int* __restrict__ nbs, const int* __restrict__ eis,
              const int* __restrict__ nbn, const int* __restrict__ ein,
              __hip_bfloat16* __restrict__ A)
{
  const int mt = blockIdx.x, tid = threadIdx.x;
  __shared__ int   nd[16];     // node id (L0) or g_out1 row (L1)
  __shared__ float dtl[16];
  __shared__ int   eil[16];
  if (tid < 16) {
    int m = mt * 16 + tid;
    int r = m / KN;
    if (L == 0) {
      if (r < NB) { nd[tid] = nbs[m]; dtl[tid] = tsv[r] - ets[m]; eil[tid] = eis[m]; }
      else {
        int mm = m - NB * KN; int rr = r - NB;
        nd[tid] = nbn[mm]; dtl[tid] = tsv[rr / KN] - etn[mm]; eil[tid] = ein[mm];
      }
    } else {
      nd[tid] = NB + m;        // neigh_emb row in g_out1
      dtl[tid] = tsv[r] - ets[m];
      eil[tid] = eis[m];
    }
  }
  __syncthreads();
  #pragma unroll
  for (int s = 0; s < 3; ++s) {
    int slot = s * 256 + tid;          // 768 = 48 kg * 16 rl
    int kg = slot >> 4, rl = slot & 15;
    float v[8];
    if (kg < 16) {                     // neighbor features
      int k0 = kg * 8;
      if (L == 0) {
        const float4* pm = (const float4*)(mem + (size_t)nd[rl] * DF + k0);
        const float4* pn = (const float4*)(nf  + (size_t)nd[rl] * DF + k0);
        float4 a0 = pm[0], a1 = pm[1], b0 = pn[0], b1 = pn[1];
        v[0]=a0.x+b0.x; v[1]=a0.y+b0.y; v[2]=a0.z+b0.z; v[3]=a0.w+b0.w;
        v[4]=a1.x+b1.x; v[5]=a1.y+b1.y; v[6]=a1.z+b1.z; v[7]=a1.w+b1.w;
      } else {
        const float4* p = (const float4*)(g_out1 + (size_t)nd[rl] * DF + k0);
        float4 a0 = p[0], a1 = p[1];
        v[0]=a0.x; v[1]=a0.y; v[2]=a0.z; v[3]=a0.w;
        v[4]=a1.x; v[5]=a1.y; v[6]=a1.z; v[7]=a1.w;
      }
    } else if (kg < 32) {              // time encoding
      int k0 = kg * 8 - DF;
      float d = dtl[rl];
      const float4* pw = (const float4*)(tw + k0);
      const float4* pb = (const float4*)(tb + k0);
      float4 w0 = pw[0], w1 = pw[1], b0 = pb[0], b1 = pb[1];
      v[0]=cosf(d*w0.x+b0.x); v[1]=cosf(d*w0.y+b0.y); v[2]=cosf(d*w0.z+b0.z); v[3]=cosf(d*w0.w+b0.w);
      v[4]=cosf(d*w1.x+b1.x); v[5]=cosf(d*w1.y+b1.y); v[6]=cosf(d*w1.z+b1.z); v[7]=cosf(d*w1.w+b1.w);
    } else {                           // edge features
      int k0 = kg * 8 - 2 * DF;
      const float4* p = (const float4*)(ef + (size_t)eil[rl] * DF + k0);
      float4 a0 = p[0], a1 = p[1];
      v[0]=a0.x; v[1]=a0.y; v[2]=a0.z; v[3]=a0.w;
      v[4]=a1.x; v[5]=a1.y; v[6]=a1.z; v[7]=a1.w;
    }
    s16x8 o;
    #pragma unroll
    for (int e = 0; e < 8; ++e) o[e] = f2bf(v[e]);
    *(s16x8*)(A + ((size_t)(mt * KG + kg) * 16 + rl) * 8) = o;
  }
}

// ============ GEMM: C[M,512] = A @ B (MFMA 16x16x32 bf16) ============
// BM=64, BN=256, BK=32; 256 threads (4 waves); grid = (M/64)*2
__global__ __launch_bounds__(256)
void k_gemm(const __hip_bfloat16* __restrict__ A,
            const __hip_bfloat16* __restrict__ B,
            __hip_bfloat16* __restrict__ C)
{
  __shared__ __hip_bfloat16 smem[2 * 10240];   // per buf: A 2048 + B 8192 elems
  const int tid = threadIdx.x;
  const int lt  = tid & 63;         // lane
  const int wn  = tid >> 6;         // wave = n-quadrant
  const int bm  = blockIdx.x >> 1;
  const int bn  = blockIdx.x & 1;
  const int rl  = lt & 15, kgs = lt >> 4;

  f32x4 acc[4][4];
  #pragma unroll
  for (int i = 0; i < 4; ++i)
    #pragma unroll
    for (int j = 0; j < 4; ++j) acc[i][j] = (f32x4){0.f, 0.f, 0.f, 0.f};

  #define STAGE(T, BUF) {                                                        \
    __hip_bfloat16* Ab_ = smem + (BUF) * 10240;                                  \
    __hip_bfloat16* Bb_ = Ab_ + 2048;                                            \
    int mtl_ = tid >> 6;                                                         \
    s16x8 xa_ = *(const s16x8*)(A + ((size_t)(bm*4 + mtl_)*KG + (T)*4)*128 + lt*8); \
    *(s16x8*)(Ab_ + mtl_*512 + lt*8) = xa_;                                      \
    _Pragma("unroll")                                                            \
    for (int rep_ = 0; rep_ < 4; ++rep_) {                                       \
      int ntl_ = mtl_*4 + rep_;                                                  \
      s16x8 xb_ = *(const s16x8*)(B + ((size_t)(bn*16 + ntl_)*KG + (T)*4)*128 + lt*8); \
      *(s16x8*)(Bb_ + ntl_*512 + lt*8) = xb_;                                    \
    } }

  STAGE(0, 0);
  __syncthreads();
  int buf = 0;
  for (int t = 0; t < 12; ++t) {
    if (t < 11) STAGE(t + 1, buf ^ 1);
    const __hip_bfloat16* Ab = smem + buf * 10240;
    const __hip_bfloat16* Bb = Ab + 2048;
    s16x8 af[4], bfm[4];
    #pragma unroll
    for (int mtl = 0; mtl < 4; ++mtl)
      af[mtl] = *(const s16x8*)(Ab + ((mtl*4 + kgs)*16 + rl)*8);
    #pragma unroll
    for (int ntl = 0; ntl < 4; ++ntl)
      bfm[ntl] = *(const s16x8*)(Bb + (((wn*4 + ntl)*4 + kgs)*16 + rl)*8);
    #pragma unroll
    for (int mtl = 0; mtl < 4; ++mtl)
      #pragma unroll
      for (int ntl = 0; ntl < 4; ++ntl)
        acc[mtl][ntl] = __builtin_amdgcn_mfma_f32_16x16x32_bf16(af[mtl], bfm[ntl], acc[mtl][ntl], 0, 0, 0);
    __syncthreads();
    buf ^= 1;
  }
  // epilogue: C row-major bf16; C layout from m89: col=lane&15, row=(lane>>4)*4+reg
  #pragma unroll
  for (int mtl = 0; mtl < 4; ++mtl) {
    #pragma unroll
    for (int ntl = 0; ntl < 4; ++ntl) {
      size_t grow0 = (size_t)bm*64 + mtl*16 + kgs*4;
      int gcol = bn*256 + wn*64 + ntl*16 + rl;
      #pragma unroll
      for (int rg = 0; rg < 4; ++rg)
        C[(grow0 + rg)*NOUT + gcol] = __float2bfloat16(acc[mtl][ntl][rg]);
    }
  }
  #undef STAGE
}

// ============ attention + merge (round-3 logic, k/v from C) ============
template<int L>
__global__ __launch_bounds__(256)
void k_attn(const float* __restrict__ nf, const float* __restrict__ mem,
            const float* __restrict__ tb,
            const float* __restrict__ Wq, const float* __restrict__ bq,
            const float* __restrict__ bk, const float* __restrict__ bv,
            const float* __restrict__ Wo, const float* __restrict__ bo,
            const float* __restrict__ fc1w, const float* __restrict__ fc1b,
            const float* __restrict__ fc2w, const float* __restrict__ fc2b,
            const int* __restrict__ srcn, const int* __restrict__ nbrs_src,
            const int* __restrict__ nbrs_nbr,
            const __hip_bfloat16* __restrict__ C,
            float* __restrict__ outf)
{
  const int r   = blockIdx.x;
  const int tid = threadIdx.x;
  const int lane = tid & 63;
  const int wid  = tid >> 6;

  __shared__ float sf[DF];
  __shared__ float cte[DF];
  __shared__ float oatt[DQ];
  __shared__ float oo[DQ];
  __shared__ float h1[DF];
  __shared__ float part[4][KN];
  __shared__ float attnw[2][KN];
  __shared__ int   nid[KN];
  __shared__ unsigned int mbits;

  const float* wq  = Wq   + L*DQ*DQ;
  const float* wo  = Wo   + L*DQ*DQ;
  const float* f1w = fc1w + L*(DQ+DF)*DF;
  const float* f2w = fc2w + L*DF*DF;
  const float* bqv = bq   + L*DQ;
  const float* bkv = bk   + L*DQ;
  const float* bvv = bv   + L*DQ;
  const float* bov = bo   + L*DQ;
  const float* f1b = fc1b + L*DF;
  const float* f2b = fc2b + L*DF;

  if (tid < KN) {
    int j = tid;
    if (L == 0) {
      if (r < NB) nid[j] = nbrs_src[r*KN + j];
      else        nid[j] = nbrs_nbr[(r - NB)*KN + j];
    } else {
      nid[j] = nbrs_src[r*KN + j];
    }
  }
  __syncthreads();

  if (tid == 0) {
    unsigned int mb = 0;
    for (int j = 0; j < KN; ++j) mb |= (nid[j] == 0 ? 1u : 0u) << j;
    mbits = mb;
  }

  if (tid < DF) {
    if (L == 0) {
      int node = (r < NB) ? srcn[r] : nbrs_src[r - NB];
      sf[tid] = mem[(size_t)node*DF + tid] + nf[(size_t)node*DF + tid];
    } else {
      sf[tid] = g_out1[r*DF + tid];
    }
    cte[tid] = cosf(tb[tid]);
  }

  // k, v from GEMM output (+ biases)
  float ack[KN], acv[KN];
  {
    const __hip_bfloat16* Cb = C + (size_t)r * KN * NOUT;
    float bkc = bkv[tid], bvc = bvv[tid];
    #pragma unroll
    for (int m = 0; m < KN; ++m) {
      ack[m] = __bfloat162float(Cb[m*NOUT + tid])       + bkc;
      acv[m] = __bfloat162float(Cb[m*NOUT + 256 + tid]) + bvc;
    }
  }
  __syncthreads();

  // q projection (thread tid owns column tid)
  float qreg = bqv[tid];
  for (int c = 0; c < DF; ++c)  qreg += sf[c]  * wq[c*DQ + tid];
  for (int c = 0; c < DF; ++c)  qreg += cte[c] * wq[(DF + c)*DQ + tid];

  // scores via wave butterfly + pair-of-waves sum
  #pragma unroll
  for (int m = 0; m < KN; ++m) {
    float p = qreg * ack[m];
    p += __shfl_xor(p, 1);
    p += __shfl_xor(p, 2);
    p += __shfl_xor(p, 4);
    p += __shfl_xor(p, 8);
    p += __shfl_xor(p, 16);
    p += __shfl_xor(p, 32);
    if (lane == 0) part[wid][m] = p;
  }
  __syncthreads();

  if (tid < 2) {
    const int h = tid;
    float s[KN];
    #pragma unroll
    for (int m = 0; m < KN; ++m) {
      float v = (part[2*h][m] + part[2*h + 1][m]) * 0.08838834764831845f;
      if ((mbits >> m) & 1u) v = -1e9f;
      s[m] = v;
    }
    float mx = -3.0e38f;
    #pragma unroll
    for (int m = 0; m < KN; ++m) mx = fmaxf(mx, s[m]);
    float sum = 0.f;
    #pragma unroll
    for (int m = 0; m < KN; ++m) { s[m] = expf(s[m] - mx); sum += s[m]; }
    float inv = 1.f / sum;
    #pragma unroll
    for (int m = 0; m < KN; ++m) attnw[h][m] = s[m] * inv;
  }
  __syncthreads();

  {
    const int h = tid >> 7;
    float acc = 0.f;
    #pragma unroll
    for (int m = 0; m < KN; ++m) acc += attnw[h][m] * acv[m];
    oatt[tid] = acc;
  }
  __syncthreads();

  {
    float acc = bov[tid];
    for (int c = 0; c < DQ; ++c) acc += oatt[c] * wo[c*DQ + tid];
    if (mbits == 0xFFFFFu) acc = 0.f;
    oo[tid] = acc;
  }
  __syncthreads();

  if (tid < DF) {
    float acc = f1b[tid];
    for (int c = 0; c < DQ; ++c) acc += oo[c] * f1w[c*DF + tid];
    for (int c = 0; c < DF; ++c) acc += sf[c] * f1w[(DQ + c)*DF + tid];
    h1[tid] = fmaxf(acc, 0.f);
  }
  __syncthreads();

  if (tid < DF) {
    float acc = f2b[tid];
    for (int c = 0; c < DF; ++c) acc += h1[c] * f2w[c*DF + tid];
    if (L == 0) g_out1[r*DF + tid] = acc;
    else        outf[r*DF + tid] = acc;
  }
}

extern "C" void kernel_launch(void* const* d_in, const int* in_sizes, int n_in,
                              void* d_out, int out_size, void* d_ws, size_t ws_size,
                              hipStream_t stream) {
  (void)in_sizes; (void)n_in; (void)out_size; (void)ws_size; (void)d_ws;
  const float* nf   = (const float*)d_in[0];
  const float* ef   = (const float*)d_in[1];
  const float* mem  = (const float*)d_in[2];
  const float* tsv  = (const float*)d_in[3];
  const float* ets  = (const float*)d_in[4];
  const float* etn  = (const float*)d_in[5];
  const float* tw   = (const float*)d_in[6];
  const float* tb   = (const float*)d_in[7];
  const float* Wq   = (const float*)d_in[8];
  const float* bq   = (const float*)d_in[9];
  const float* Wk   = (const float*)d_in[10];
  const float* bk   = (const float*)d_in[11];
  const float* Wv   = (const float*)d_in[12];
  const float* bv   = (const float*)d_in[13];
  const float* Wo   = (const float*)d_in[14];
  const float* bo   = (const float*)d_in[15];
  const float* f1w  = (const float*)d_in[16];
  const float* f1b  = (const float*)d_in[17];
  const float* f2w  = (const float*)d_in[18];
  const float* f2b  = (const float*)d_in[19];
  const int* srcn   = (const int*)d_in[20];
  const int* nbs    = (const int*)d_in[21];
  const int* eis    = (const int*)d_in[22];
  const int* nbn    = (const int*)d_in[23];
  const int* ein    = (const int*)d_in[24];

  float* out = (float*)d_out;

  __hip_bfloat16 *A0, *C0, *A1, *C1, *Bt;
  hipGetSymbolAddress((void**)&A0, HIP_SYMBOL(g_A0));
  hipGetSymbolAddress((void**)&C0, HIP_SYMBOL(g_C0));
  hipGetSymbolAddress((void**)&A1, HIP_SYMBOL(g_A1));
  hipGetSymbolAddress((void**)&C1, HIP_SYMBOL(g_C1));
  hipGetSymbolAddress((void**)&Bt, HIP_SYMBOL(g_Bt));

  hipLaunchKernelGGL(k_wconv, dim3(192), dim3(256), 0, stream, Wk, Wv);
  hipLaunchKernelGGL((k_gather<0>), dim3(M0/16), dim3(256), 0, stream,
      nf, ef, mem, tsv, ets, etn, tw, tb, nbs, eis, nbn, ein, A0);
  hipLaunchKernelGGL(k_gemm, dim3((M0/64)*2), dim3(256), 0, stream, A0, Bt, C0);
  hipLaunchKernelGGL((k_attn<0>), dim3(NR1), dim3(256), 0, stream,
      nf, mem, tb, Wq, bq, bk, bv, Wo, bo, f1w, f1b, f2w, f2b,
      srcn, nbs, nbn, C0, (float*)nullptr);
  hipLaunchKernelGGL((k_gather<1>), dim3(M1/16), dim3(256), 0, stream,
      nf, ef, mem, tsv, ets, etn, tw, tb, nbs, eis, nbn, ein, A1);
  hipLaunchKernelGGL(k_gemm, dim3((M1/64)*2), dim3(256), 0, stream,
      A1, Bt + 32*KG*128, C1);
  hipLaunchKernelGGL((k_attn<1>), dim3(NB), dim3(256), 0, stream,
      nf, mem, tb, Wq, bq, bk, bv, Wo, bo, f1w, f1b, f2w, f2b,
      srcn, nbs, nbn, C1, out);
}

// Round 5
// 1661.596 us; speedup vs baseline: 4.3472x; 1.6229x over previous
//
#include <hip/hip_runtime.h>
#include <hip/hip_bf16.h>

#define NB    2048
#define KN    20
#define DF    128
#define DQ    256
#define DKI   384          // k_in width
#define NR1   43008        // layer-1 rows (2048 src + 40960 neighbors)
#define M0    860160       // NR1*KN edge rows (layer-1 GEMM M)
#define M1    40960        // NB*KN (layer-2 GEMM M)
#define KG    48           // DKI/8 k-groups
#define NOUT  512          // k(256) | v(256)

typedef short s16x8 __attribute__((ext_vector_type(8)));
typedef float f32x4 __attribute__((ext_vector_type(4)));

// ---- static device scratch ----
__device__ __hip_bfloat16 g_A0[(size_t)M0 * DKI];     // 660 MB, tiled layout
__device__ __hip_bfloat16 g_C0[(size_t)M0 * NOUT];    // 880 MB, row-major
__device__ __hip_bfloat16 g_A1[(size_t)M1 * DKI];
__device__ __hip_bfloat16 g_C1[(size_t)M1 * NOUT];
__device__ __hip_bfloat16 g_Bt[2 * 32 * KG * 16 * 8]; // weights, tiled
__device__ float g_out1[NR1 * DF];                    // layer-1 outputs

__device__ __forceinline__ short f2bf(float v) {
  union { __hip_bfloat16 h; short s; } u; u.h = __float2bfloat16(v); return u.s;
}
__device__ __forceinline__ float bf2f(short s) {
  union { unsigned u; float f; } x; x.u = ((unsigned)(unsigned short)s) << 16; return x.f;
}

// ============ weight conversion: [Wk|Wv] f32 -> bf16 tiled ============
__global__ __launch_bounds__(256)
void k_wconv(const float* __restrict__ Wk, const float* __restrict__ Wv) {
  int slot = blockIdx.x * 256 + threadIdx.x;   // 2*32*48*16 = 49152 slots
  int cl = slot & 15;
  int t1 = slot >> 4;
  int kg = t1 % KG;
  int t2 = t1 / KG;          // L*32 + nt
  int nt = t2 & 31;
  int L  = t2 >> 5;
  int c  = nt * 16 + cl;
  const float* src; int cc;
  if (c < 256) { src = Wk + (size_t)L * DKI * DQ; cc = c; }
  else         { src = Wv + (size_t)L * DKI * DQ; cc = c - 256; }
  s16x8 o;
  #pragma unroll
  for (int e = 0; e < 8; ++e) o[e] = f2bf(src[(size_t)(kg * 8 + e) * 256 + cc]);
  *(s16x8*)(g_Bt + (size_t)slot * 8) = o;
}

// ============ gather/encode: build A in tiled bf16 layout ============
// A_t[mt][kg][16 row][8 k]; edge row m = r*KN + j
template<int L>
__global__ __launch_bounds__(256)
void k_gather(const float* __restrict__ nf, const float* __restrict__ ef,
              const float* __restrict__ mem, const float* __restrict__ tsv,
              const float* __restrict__ ets, const float* __restrict__ etn,
              const float* __restrict__ tw,  const float* __restrict__ tb,
              const int* __restrict__ nbs, const int* __restrict__ eis,
              const int* __restrict__ nbn, const int* __restrict__ ein,
              __hip_bfloat16* __restrict__ A)
{
  const int mt = blockIdx.x, tid = threadIdx.x;
  __shared__ int   nd[16];
  __shared__ float dtl[16];
  __shared__ int   eil[16];
  if (tid < 16) {
    int m = mt * 16 + tid;
    int r = m / KN;
    if (L == 0) {
      if (r < NB) { nd[tid] = nbs[m]; dtl[tid] = tsv[r] - ets[m]; eil[tid] = eis[m]; }
      else {
        int mm = m - NB * KN; int rr = r - NB;
        nd[tid] = nbn[mm]; dtl[tid] = tsv[rr / KN] - etn[mm]; eil[tid] = ein[mm];
      }
    } else {
      nd[tid] = NB + m;
      dtl[tid] = tsv[r] - ets[m];
      eil[tid] = eis[m];
    }
  }
  __syncthreads();
  #pragma unroll
  for (int s = 0; s < 3; ++s) {
    int slot = s * 256 + tid;          // 768 = 48 kg * 16 rl
    int kg = slot >> 4, rl = slot & 15;
    float v[8];
    if (kg < 16) {
      int k0 = kg * 8;
      if (L == 0) {
        const float4* pm = (const float4*)(mem + (size_t)nd[rl] * DF + k0);
        const float4* pn = (const float4*)(nf  + (size_t)nd[rl] * DF + k0);
        float4 a0 = pm[0], a1 = pm[1], b0 = pn[0], b1 = pn[1];
        v[0]=a0.x+b0.x; v[1]=a0.y+b0.y; v[2]=a0.z+b0.z; v[3]=a0.w+b0.w;
        v[4]=a1.x+b1.x; v[5]=a1.y+b1.y; v[6]=a1.z+b1.z; v[7]=a1.w+b1.w;
      } else {
        const float4* p = (const float4*)(g_out1 + (size_t)nd[rl] * DF + k0);
        float4 a0 = p[0], a1 = p[1];
        v[0]=a0.x; v[1]=a0.y; v[2]=a0.z; v[3]=a0.w;
        v[4]=a1.x; v[5]=a1.y; v[6]=a1.z; v[7]=a1.w;
      }
    } else if (kg < 32) {
      int k0 = kg * 8 - DF;
      float d = dtl[rl];
      const float4* pw = (const float4*)(tw + k0);
      const float4* pb = (const float4*)(tb + k0);
      float4 w0 = pw[0], w1 = pw[1], b0 = pb[0], b1 = pb[1];
      v[0]=cosf(d*w0.x+b0.x); v[1]=cosf(d*w0.y+b0.y); v[2]=cosf(d*w0.z+b0.z); v[3]=cosf(d*w0.w+b0.w);
      v[4]=cosf(d*w1.x+b1.x); v[5]=cosf(d*w1.y+b1.y); v[6]=cosf(d*w1.z+b1.z); v[7]=cosf(d*w1.w+b1.w);
    } else {
      int k0 = kg * 8 - 2 * DF;
      const float4* p = (const float4*)(ef + (size_t)eil[rl] * DF + k0);
      float4 a0 = p[0], a1 = p[1];
      v[0]=a0.x; v[1]=a0.y; v[2]=a0.z; v[3]=a0.w;
      v[4]=a1.x; v[5]=a1.y; v[6]=a1.z; v[7]=a1.w;
    }
    s16x8 o;
    #pragma unroll
    for (int e = 0; e < 8; ++e) o[e] = f2bf(v[e]);
    *(s16x8*)(A + ((size_t)(mt * KG + kg) * 16 + rl) * 8) = o;
  }
}

// ============ GEMM: C[M,512] = A @ B, tile 128x256, 4 waves ============
__global__ __launch_bounds__(256, 2)
void k_gemm(const __hip_bfloat16* __restrict__ A,
            const __hip_bfloat16* __restrict__ B,
            __hip_bfloat16* __restrict__ C)
{
  __shared__ __hip_bfloat16 smem[2 * 12288];   // per buf: A 4096 + B 8192 elems
  const int tid  = threadIdx.x;
  const int lane = tid & 63;
  const int wid  = tid >> 6;
  const int wm   = wid >> 1, wn = wid & 1;     // wave tile 64 x 128
  const int bm   = blockIdx.x >> 1;
  const int bn   = blockIdx.x & 1;
  const int rl   = lane & 15, kgs = lane >> 4;

  f32x4 acc[4][8];
  #pragma unroll
  for (int i = 0; i < 4; ++i)
    #pragma unroll
    for (int j = 0; j < 8; ++j) acc[i][j] = (f32x4){0.f, 0.f, 0.f, 0.f};

  #define STAGE(T, BUF) {                                                        \
    __hip_bfloat16* Ab_ = smem + (BUF) * 12288;                                  \
    __hip_bfloat16* Bb_ = Ab_ + 4096;                                            \
    _Pragma("unroll")                                                            \
    for (int i_ = 0; i_ < 2; ++i_) {                                             \
      int mt_ = wid * 2 + i_;                                                    \
      s16x8 x_ = *(const s16x8*)(A + ((size_t)(bm*8 + mt_)*KG + (T)*4)*128 + lane*8); \
      *(s16x8*)(Ab_ + mt_*512 + lane*8) = x_;                                    \
    }                                                                            \
    _Pragma("unroll")                                                            \
    for (int j_ = 0; j_ < 4; ++j_) {                                             \
      int nt_ = wid * 4 + j_;                                                    \
      s16x8 x_ = *(const s16x8*)(B + ((size_t)(bn*16 + nt_)*KG + (T)*4)*128 + lane*8); \
      *(s16x8*)(Bb_ + nt_*512 + lane*8) = x_;                                    \
    } }

  STAGE(0, 0);
  __syncthreads();
  int buf = 0;
  for (int t = 0; t < 12; ++t) {
    if (t < 11) STAGE(t + 1, buf ^ 1);
    const __hip_bfloat16* Ab = smem + buf * 12288;
    const __hip_bfloat16* Bb = Ab + 4096;
    s16x8 af[4], bfm[8];
    #pragma unroll
    for (int mtl = 0; mtl < 4; ++mtl)
      af[mtl] = *(const s16x8*)(Ab + ((wm*4 + mtl)*4 + kgs)*128 + rl*8);
    #pragma unroll
    for (int ntl = 0; ntl < 8; ++ntl)
      bfm[ntl] = *(const s16x8*)(Bb + ((wn*8 + ntl)*4 + kgs)*128 + rl*8);
    #pragma unroll
    for (int mtl = 0; mtl < 4; ++mtl)
      #pragma unroll
      for (int ntl = 0; ntl < 8; ++ntl)
        acc[mtl][ntl] = __builtin_amdgcn_mfma_f32_16x16x32_bf16(af[mtl], bfm[ntl], acc[mtl][ntl], 0, 0, 0);
    __syncthreads();
    buf ^= 1;
  }
  // epilogue: C row-major bf16; C/D layout: col=lane&15, row=(lane>>4)*4+reg
  #pragma unroll
  for (int mtl = 0; mtl < 4; ++mtl) {
    #pragma unroll
    for (int ntl = 0; ntl < 8; ++ntl) {
      size_t grow0 = (size_t)bm*128 + wm*64 + mtl*16 + kgs*4;
      int gcol = bn*256 + wn*128 + ntl*16 + rl;
      #pragma unroll
      for (int rg = 0; rg < 4; ++rg)
        C[(grow0 + rg)*NOUT + gcol] = __float2bfloat16(acc[mtl][ntl][rg]);
    }
  }
  #undef STAGE
}

// ============ batched attention + merge: 8 rows per block ============
template<int L>
__global__ __launch_bounds__(256)
void k_attn(const float* __restrict__ nf, const float* __restrict__ mem,
            const float* __restrict__ tb,
            const float* __restrict__ Wq, const float* __restrict__ bq,
            const float* __restrict__ bk, const float* __restrict__ bv,
            const float* __restrict__ Wo, const float* __restrict__ bo,
            const float* __restrict__ fc1w, const float* __restrict__ fc1b,
            const float* __restrict__ fc2w, const float* __restrict__ fc2b,
            const int* __restrict__ srcn, const int* __restrict__ nbs,
            const int* __restrict__ nbn,
            const __hip_bfloat16* __restrict__ C,
            float* __restrict__ outf)
{
  const int b0  = blockIdx.x * 8;
  const int tid = threadIdx.x;

  __shared__ float sf_sh[8][DF];     // src features
  __shared__ float cte_sh[DF];       // cos(tb)
  __shared__ float q_sh[8][DQ];      // q; reused as oo after Wo
  __shared__ float o_sh[8][DQ];      // attn out; reused as fc2 partials
  __shared__ float h1_sh[8][DF];
  __shared__ float s_sh[8][2][KN];   // scores -> attn weights
  __shared__ float bk_sh[DQ];
  __shared__ unsigned int mb_sh[8];
  __shared__ int allm_sh[8];

  const float* wq  = Wq   + L*DQ*DQ;
  const float* wo  = Wo   + L*DQ*DQ;
  const float* f1w = fc1w + L*(DQ+DF)*DF;
  const float* f2w = fc2w + L*DF*DF;
  const float* bqv = bq   + L*DQ;
  const float* bkv = bk   + L*DQ;
  const float* bvv = bv   + L*DQ;
  const float* bov = bo   + L*DQ;
  const float* f1b = fc1b + L*DF;
  const float* f2b = fc2b + L*DF;

  // ---- phase A: metadata + src features ----
  if (tid < 8) {
    int r = b0 + tid;
    const int* nb = (L == 0) ? ((r < NB) ? (nbs + r*KN) : (nbn + (size_t)(r - NB)*KN))
                             : (nbs + r*KN);
    unsigned mb = 0;
    for (int j = 0; j < KN; ++j) mb |= (nb[j] == 0 ? 1u : 0u) << j;
    mb_sh[tid] = mb;
    allm_sh[tid] = (mb == 0xFFFFFu) ? 1 : 0;
  }
  bk_sh[tid] = bkv[tid];
  if (tid < DF) cte_sh[tid] = cosf(tb[tid]);
  for (int i = tid; i < 8*DF; i += 256) {
    int rr = i >> 7, d = i & 127;
    int r = b0 + rr;
    float v;
    if (L == 0) {
      int node = (r < NB) ? srcn[r] : nbs[r - NB];
      v = mem[(size_t)node*DF + d] + nf[(size_t)node*DF + d];
    } else {
      v = g_out1[(size_t)r*DF + d];
    }
    sf_sh[rr][d] = v;
  }
  __syncthreads();

  // ---- phase B: q projection (thread owns column tid, 8 rows) ----
  {
    float t0[8];
    #pragma unroll
    for (int rr = 0; rr < 8; ++rr) t0[rr] = 0.f;
    float qc = 0.f;
    for (int c = 0; c < DF; c += 4) {
      float w0 = wq[(c+0)*DQ + tid];
      float w1 = wq[(c+1)*DQ + tid];
      float w2 = wq[(c+2)*DQ + tid];
      float w3 = wq[(c+3)*DQ + tid];
      #pragma unroll
      for (int rr = 0; rr < 8; ++rr) {
        float4 s4 = *(const float4*)&sf_sh[rr][c];
        t0[rr] += s4.x*w0 + s4.y*w1 + s4.z*w2 + s4.w*w3;
      }
      float w4 = wq[(DF+c+0)*DQ + tid];
      float w5 = wq[(DF+c+1)*DQ + tid];
      float w6 = wq[(DF+c+2)*DQ + tid];
      float w7 = wq[(DF+c+3)*DQ + tid];
      float4 c4 = *(const float4*)&cte_sh[c];
      qc += c4.x*w4 + c4.y*w5 + c4.z*w6 + c4.w*w7;
    }
    float qb = bqv[tid] + qc;
    #pragma unroll
    for (int rr = 0; rr < 8; ++rr) q_sh[rr][tid] = t0[rr] + qb;
  }
  __syncthreads();

  // ---- phase C: scores, thread per (row, neighbor) ----
  if (tid < 8*KN) {
    int rr = tid / KN;
    int m  = tid - rr*KN;
    const __hip_bfloat16* Ck = C + ((size_t)(b0 + rr)*KN + m)*NOUT;
    float s0 = 0.f, s1 = 0.f;
    for (int c = 0; c < DF; c += 8) {
      s16x8 kx = *(const s16x8*)(Ck + c);
      float4 qa = *(const float4*)&q_sh[rr][c];
      float4 qb4 = *(const float4*)&q_sh[rr][c+4];
      float4 ba = *(const float4*)&bk_sh[c];
      float4 bb = *(const float4*)&bk_sh[c+4];
      s0 += (bf2f(kx[0])+ba.x)*qa.x + (bf2f(kx[1])+ba.y)*qa.y
          + (bf2f(kx[2])+ba.z)*qa.z + (bf2f(kx[3])+ba.w)*qa.w
          + (bf2f(kx[4])+bb.x)*qb4.x + (bf2f(kx[5])+bb.y)*qb4.y
          + (bf2f(kx[6])+bb.z)*qb4.z + (bf2f(kx[7])+bb.w)*qb4.w;
      s16x8 ky = *(const s16x8*)(Ck + DF + c);
      float4 qc4 = *(const float4*)&q_sh[rr][DF+c];
      float4 qd4 = *(const float4*)&q_sh[rr][DF+c+4];
      float4 bc = *(const float4*)&bk_sh[DF+c];
      float4 bd = *(const float4*)&bk_sh[DF+c+4];
      s1 += (bf2f(ky[0])+bc.x)*qc4.x + (bf2f(ky[1])+bc.y)*qc4.y
          + (bf2f(ky[2])+bc.z)*qc4.z + (bf2f(ky[3])+bc.w)*qc4.w
          + (bf2f(ky[4])+bd.x)*qd4.x + (bf2f(ky[5])+bd.y)*qd4.y
          + (bf2f(ky[6])+bd.z)*qd4.z + (bf2f(ky[7])+bd.w)*qd4.w;
    }
    s_sh[rr][0][m] = s0 * 0.08838834764831845f;
    s_sh[rr][1][m] = s1 * 0.08838834764831845f;
  }
  __syncthreads();

  // ---- phase D: masked softmax, thread per (row, head) ----
  if (tid < 16) {
    int rr = tid >> 1, h = tid & 1;
    unsigned mb = mb_sh[rr];
    float s[KN];
    float mx = -3.0e38f;
    #pragma unroll
    for (int m = 0; m < KN; ++m) {
      float v = s_sh[rr][h][m];
      if ((mb >> m) & 1u) v = -1e9f;
      s[m] = v;
      mx = fmaxf(mx, v);
    }
    float sum = 0.f;
    #pragma unroll
    for (int m = 0; m < KN; ++m) { s[m] = expf(s[m] - mx); sum += s[m]; }
    float inv = 1.f / sum;
    #pragma unroll
    for (int m = 0; m < KN; ++m) s_sh[rr][h][m] = s[m] * inv;
  }
  __syncthreads();

  // ---- phase E: PV (thread owns column tid; v-bias folded: sum(attn)=1) ----
  {
    const int h = tid >> 7;
    const float bvc = bvv[tid];
    #pragma unroll
    for (int rr = 0; rr < 8; ++rr) {
      const __hip_bfloat16* Cv = C + ((size_t)(b0 + rr)*KN)*NOUT + 256 + tid;
      float acc = 0.f;
      #pragma unroll
      for (int m = 0; m < KN; ++m)
        acc += s_sh[rr][h][m] * __bfloat162float(Cv[(size_t)m*NOUT]);
      o_sh[rr][tid] = acc + bvc;
    }
  }
  __syncthreads();

  // ---- phase F: Wo projection + all-masked zero (into q_sh) ----
  {
    float oo[8];
    float bo_c = bov[tid];
    #pragma unroll
    for (int rr = 0; rr < 8; ++rr) oo[rr] = bo_c;
    for (int c = 0; c < DQ; c += 4) {
      float w0 = wo[(c+0)*DQ + tid];
      float w1 = wo[(c+1)*DQ + tid];
      float w2 = wo[(c+2)*DQ + tid];
      float w3 = wo[(c+3)*DQ + tid];
      #pragma unroll
      for (int rr = 0; rr < 8; ++rr) {
        float4 o4 = *(const float4*)&o_sh[rr][c];
        oo[rr] += o4.x*w0 + o4.y*w1 + o4.z*w2 + o4.w*w3;
      }
    }
    #pragma unroll
    for (int rr = 0; rr < 8; ++rr)
      q_sh[rr][tid] = allm_sh[rr] ? 0.f : oo[rr];
  }
  __syncthreads();

  // ---- phase G: fc1 + relu (two wave-halves split the 384-dim input) ----
  {
    const int col  = tid & 127;
    const int part = tid >> 7;
    float hv[8];
    #pragma unroll
    for (int rr = 0; rr < 8; ++rr) hv[rr] = 0.f;
    if (part == 0) {
      for (int c = 0; c < 192; ++c) {
        float w = f1w[c*DF + col];
        #pragma unroll
        for (int rr = 0; rr < 8; ++rr) hv[rr] += q_sh[rr][c] * w;
      }
    } else {
      for (int c = 192; c < 256; ++c) {
        float w = f1w[c*DF + col];
        #pragma unroll
        for (int rr = 0; rr < 8; ++rr) hv[rr] += q_sh[rr][c] * w;
      }
      for (int d = 0; d < DF; ++d) {
        float w = f1w[(DQ + d)*DF + col];
        #pragma unroll
        for (int rr = 0; rr < 8; ++rr) hv[rr] += sf_sh[rr][d] * w;
      }
    }
    if (part == 0) {
      #pragma unroll
      for (int rr = 0; rr < 8; ++rr) h1_sh[rr][col] = hv[rr];
    }
    __syncthreads();
    if (part == 1) {
      float b = f1b[col];
      #pragma unroll
      for (int rr = 0; rr < 8; ++rr)
        h1_sh[rr][col] = fmaxf(h1_sh[rr][col] + hv[rr] + b, 0.f);
    }
  }
  __syncthreads();

  // ---- phase H: fc2 + write ----
  {
    const int col  = tid & 127;
    const int part = tid >> 7;
    float ov[8];
    #pragma unroll
    for (int rr = 0; rr < 8; ++rr) ov[rr] = 0.f;
    for (int i = 0; i < 64; ++i) {
      int c = part*64 + i;
      float w = f2w[c*DF + col];
      #pragma unroll
      for (int rr = 0; rr < 8; ++rr) ov[rr] += h1_sh[rr][c] * w;
    }
    if (part == 0) {
      #pragma unroll
      for (int rr = 0; rr < 8; ++rr) o_sh[rr][col] = ov[rr];
    }
    __syncthreads();
    if (part == 1) {
      float b = f2b[col];
      #pragma unroll
      for (int rr = 0; rr < 8; ++rr) {
        float res = o_sh[rr][col] + ov[rr] + b;
        int r = b0 + rr;
        if (L == 0) g_out1[(size_t)r*DF + col] = res;
        else        outf[(size_t)r*DF + col] = res;
      }
    }
  }
}

extern "C" void kernel_launch(void* const* d_in, const int* in_sizes, int n_in,
                              void* d_out, int out_size, void* d_ws, size_t ws_size,
                              hipStream_t stream) {
  (void)in_sizes; (void)n_in; (void)out_size; (void)ws_size; (void)d_ws;
  const float* nf   = (const float*)d_in[0];
  const float* ef   = (const float*)d_in[1];
  const float* mem  = (const float*)d_in[2];
  const float* tsv  = (const float*)d_in[3];
  const float* ets  = (const float*)d_in[4];
  const float* etn  = (const float*)d_in[5];
  const float* tw   = (const float*)d_in[6];
  const float* tb   = (const float*)d_in[7];
  const float* Wq   = (const float*)d_in[8];
  const float* bq   = (const float*)d_in[9];
  const float* Wk   = (const float*)d_in[10];
  const float* bk   = (const float*)d_in[11];
  const float* Wv   = (const float*)d_in[12];
  const float* bv   = (const float*)d_in[13];
  const float* Wo   = (const float*)d_in[14];
  const float* bo   = (const float*)d_in[15];
  const float* f1w  = (const float*)d_in[16];
  const float* f1b  = (const float*)d_in[17];
  const float* f2w  = (const float*)d_in[18];
  const float* f2b  = (const float*)d_in[19];
  const int* srcn   = (const int*)d_in[20];
  const int* nbs    = (const int*)d_in[21];
  const int* eis    = (const int*)d_in[22];
  const int* nbn    = (const int*)d_in[23];
  const int* ein    = (const int*)d_in[24];

  float* out = (float*)d_out;

  __hip_bfloat16 *A0, *C0, *A1, *C1, *Bt;
  hipGetSymbolAddress((void**)&A0, HIP_SYMBOL(g_A0));
  hipGetSymbolAddress((void**)&C0, HIP_SYMBOL(g_C0));
  hipGetSymbolAddress((void**)&A1, HIP_SYMBOL(g_A1));
  hipGetSymbolAddress((void**)&C1, HIP_SYMBOL(g_C1));
  hipGetSymbolAddress((void**)&Bt, HIP_SYMBOL(g_Bt));

  hipLaunchKernelGGL(k_wconv, dim3(192), dim3(256), 0, stream, Wk, Wv);
  hipLaunchKernelGGL((k_gather<0>), dim3(M0/16), dim3(256), 0, stream,
      nf, ef, mem, tsv, ets, etn, tw, tb, nbs, eis, nbn, ein, A0);
  hipLaunchKernelGGL(k_gemm, dim3((M0/128)*2), dim3(256), 0, stream, A0, Bt, C0);
  hipLaunchKernelGGL((k_attn<0>), dim3(NR1/8), dim3(256), 0, stream,
      nf, mem, tb, Wq, bq, bk, bv, Wo, bo, f1w, f1b, f2w, f2b,
      srcn, nbs, nbn, C0, (float*)nullptr);
  hipLaunchKernelGGL((k_gather<1>), dim3(M1/16), dim3(256), 0, stream,
      nf, ef, mem, tsv, ets, etn, tw, tb, nbs, eis, nbn, ein, A1);
  hipLaunchKernelGGL(k_gemm, dim3((M1/128)*2), dim3(256), 0, stream,
      A1, Bt + 32*KG*128, C1);
  hipLaunchKernelGGL((k_attn<1>), dim3(NB/8), dim3(256), 0, stream,
      nf, mem, tb, Wq, bq, bk, bv, Wo, bo, f1w, f1b, f2w, f2b,
      srcn, nbs, nbn, C1, out);
}

// Round 6
// 1377.520 us; speedup vs baseline: 5.2437x; 1.2062x over previous
//
#include <hip/hip_runtime.h>
#include <hip/hip_bf16.h>

#define NB    2048
#define KN    20
#define DF    128
#define DQ    256
#define DKI   384
#define NR1   43008        // layer-1 rows (2048 src + 40960 neighbors)

// static device scratch
__device__ float g_WkT[2 * 256 * 384];   // WkT[L][co][i] = Wk[L][i][co]
__device__ float g_out1[NR1 * DF];       // layer-1 outputs

// ---- transpose Wk once per call (tiny) ----
__global__ __launch_bounds__(256)
void k_wkt(const float* __restrict__ Wk) {
  int idx = blockIdx.x * 256 + threadIdx.x;      // 2*256*384 = 196608
  int i  = idx % 384;
  int t  = idx / 384;
  int co = t & 255;
  int L  = t >> 8;
  g_WkT[idx] = Wk[(size_t)L * DKI * DQ + (size_t)i * DQ + co];
}

// ---- fused TGN layer: 8 graph rows per block, 256 threads ----
template<int L>
__global__ __launch_bounds__(256)
void k_fused(const float* __restrict__ nf,  const float* __restrict__ ef,
             const float* __restrict__ mem, const float* __restrict__ tsv,
             const float* __restrict__ ets, const float* __restrict__ etn,
             const float* __restrict__ tw,  const float* __restrict__ tb,
             const float* __restrict__ Wq,  const float* __restrict__ bq,
             const float* __restrict__ bk,
             const float* __restrict__ Wv,  const float* __restrict__ bv,
             const float* __restrict__ Wo,  const float* __restrict__ bo,
             const float* __restrict__ fc1w, const float* __restrict__ fc1b,
             const float* __restrict__ fc2w, const float* __restrict__ fc2b,
             const int* __restrict__ srcn, const int* __restrict__ nbs,
             const int* __restrict__ eis,  const int* __restrict__ nbn,
             const int* __restrict__ ein,
             float* __restrict__ outf)
{
  const int b0  = blockIdx.x * 8;
  const int tid = threadIdx.x;

  __shared__ float sf_sh[8][DF];       // src feats; later fc2 partials
  __shared__ float cte_sh[DF];
  __shared__ float tw_sh[DF], tb_sh[DF];
  __shared__ float q_sh[8][DQ];        // q; later o (attn out)
  __shared__ float qk_sh[8][2][DKI];   // qkh; later ctx; later oo
  __shared__ float h1_sh[8][DF];
  __shared__ float s_sh[8][2][KN];
  __shared__ float aw_sh[8][2][KN];
  __shared__ float sqb_sh[8][2];
  __shared__ int   nd_sh[8][KN];
  __shared__ float dt_sh[8][KN];
  __shared__ int   ei_sh[8][KN];
  __shared__ unsigned mb_sh[8];
  __shared__ int   allm_sh[8];

  const float* wq  = Wq   + L*DQ*DQ;
  const float* wv  = Wv   + (size_t)L*DKI*DQ;
  const float* wo  = Wo   + L*DQ*DQ;
  const float* f1w = fc1w + L*(DQ+DF)*DF;
  const float* f2w = fc2w + L*DF*DF;

  // ---------- phase A: metadata + src feats + time tables ----------
  if (tid < 160) {
    int rl = tid / KN, m = tid % KN;
    int r = b0 + rl;
    int nd_, ei_; float dt_;
    if (L == 0) {
      if (r < NB) { nd_ = nbs[r*KN+m]; ei_ = eis[r*KN+m]; dt_ = tsv[r] - ets[r*KN+m]; }
      else {
        int mm = (r - NB)*KN + m;
        nd_ = nbn[mm]; ei_ = ein[mm]; dt_ = tsv[(r - NB)/KN] - etn[mm];
      }
    } else {
      nd_ = NB + r*KN + m;          // row into g_out1 (neigh_emb)
      ei_ = eis[r*KN+m];
      dt_ = tsv[r] - ets[r*KN+m];
    }
    nd_sh[rl][m] = nd_; ei_sh[rl][m] = ei_; dt_sh[rl][m] = dt_;
  }
  if (tid >= 160 && tid < 168) {
    int rl = tid - 160; int r = b0 + rl;
    const int* nb = (L == 0) ? ((r < NB) ? nbs + r*KN : nbn + (size_t)(r - NB)*KN)
                             : nbs + r*KN;
    unsigned mb = 0;
    for (int j = 0; j < KN; ++j) mb |= (nb[j] == 0 ? 1u : 0u) << j;
    mb_sh[rl] = mb; allm_sh[rl] = (mb == 0xFFFFFu);
  }
  if (tid < DF) {
    tw_sh[tid] = tw[tid];
    float tbv = tb[tid];
    tb_sh[tid] = tbv;
    cte_sh[tid] = cosf(tbv);
  }
  for (int i = tid; i < 8*DF; i += 256) {
    int rl = i >> 7, d = i & 127;
    int r = b0 + rl;
    float v;
    if (L == 0) {
      int node = (r < NB) ? srcn[r] : nbs[r - NB];
      v = mem[(size_t)node*DF + d] + nf[(size_t)node*DF + d];
    } else {
      v = g_out1[(size_t)r*DF + d];
    }
    sf_sh[rl][d] = v;
  }
  __syncthreads();

  // ---------- phase B: q projection (thread = output col) ----------
  {
    float t0[8];
    #pragma unroll
    for (int rl = 0; rl < 8; ++rl) t0[rl] = 0.f;
    float qc = 0.f;
    for (int c = 0; c < DF; c += 4) {
      float w0 = wq[(c+0)*DQ + tid];
      float w1 = wq[(c+1)*DQ + tid];
      float w2 = wq[(c+2)*DQ + tid];
      float w3 = wq[(c+3)*DQ + tid];
      #pragma unroll
      for (int rl = 0; rl < 8; ++rl) {
        float4 s4 = *(const float4*)&sf_sh[rl][c];
        t0[rl] += s4.x*w0 + s4.y*w1 + s4.z*w2 + s4.w*w3;
      }
      float w4 = wq[(DF+c+0)*DQ + tid];
      float w5 = wq[(DF+c+1)*DQ + tid];
      float w6 = wq[(DF+c+2)*DQ + tid];
      float w7 = wq[(DF+c+3)*DQ + tid];
      float4 c4 = *(const float4*)&cte_sh[c];
      qc += c4.x*w4 + c4.y*w5 + c4.z*w6 + c4.w*w7;
    }
    float qb = bq[L*DQ + tid] + qc;
    #pragma unroll
    for (int rl = 0; rl < 8; ++rl) q_sh[rl][tid] = t0[rl] + qb;
  }
  __syncthreads();

  // ---------- phase B2: sqb[r][h] = <q_h, bk_h> ----------
  if (tid < 16) {
    int rl = tid >> 1, h = tid & 1;
    float acc = 0.f;
    for (int c = 0; c < 128; ++c) acc += q_sh[rl][h*128 + c] * bk[L*DQ + h*128 + c];
    sqb_sh[rl][h] = acc;
  }

  // ---------- phase B3: qkh[r][h][i] = sum_c WkT[h*128+c][i] * q[r][h*128+c] ----------
  for (int s = tid; s < 768; s += 256) {
    int h = s / 384, i = s - h*384;
    const float* wt = g_WkT + ((size_t)L*256 + h*128)*384 + i;
    float acc[8];
    #pragma unroll
    for (int rl = 0; rl < 8; ++rl) acc[rl] = 0.f;
    #pragma unroll 4
    for (int c = 0; c < 128; ++c) {
      float w = wt[(size_t)c*384];
      #pragma unroll
      for (int rl = 0; rl < 8; ++rl) acc[rl] += q_sh[rl][h*128 + c] * w;
    }
    #pragma unroll
    for (int rl = 0; rl < 8; ++rl) qk_sh[rl][h][i] = acc[rl];
  }
  __syncthreads();

  // ---------- phase C: scores (8 lanes per edge, shfl-reduce) ----------
  #pragma unroll
  for (int it = 0; it < 5; ++it) {
    int slot = it*256 + tid;
    int mg = slot >> 3, sub = slot & 7;     // mg 0..159
    int rl = mg / KN, m = mg - rl*KN;
    int d0 = sub * 16;
    int nd_ = nd_sh[rl][m]; float dtv = dt_sh[rl][m]; int ei_ = ei_sh[rl][m];
    float a[16], t[16], e[16];
    if (L == 0) {
      #pragma unroll
      for (int j = 0; j < 4; ++j) {
        float4 x = *(const float4*)(mem + (size_t)nd_*DF + d0 + 4*j);
        float4 y = *(const float4*)(nf  + (size_t)nd_*DF + d0 + 4*j);
        a[4*j+0]=x.x+y.x; a[4*j+1]=x.y+y.y; a[4*j+2]=x.z+y.z; a[4*j+3]=x.w+y.w;
      }
    } else {
      #pragma unroll
      for (int j = 0; j < 4; ++j) {
        float4 x = *(const float4*)(g_out1 + (size_t)nd_*DF + d0 + 4*j);
        a[4*j+0]=x.x; a[4*j+1]=x.y; a[4*j+2]=x.z; a[4*j+3]=x.w;
      }
    }
    #pragma unroll
    for (int j = 0; j < 16; ++j) t[j] = cosf(dtv*tw_sh[d0+j] + tb_sh[d0+j]);
    #pragma unroll
    for (int j = 0; j < 4; ++j) {
      float4 x = *(const float4*)(ef + (size_t)ei_*DF + d0 + 4*j);
      e[4*j+0]=x.x; e[4*j+1]=x.y; e[4*j+2]=x.z; e[4*j+3]=x.w;
    }
    const float* qk0 = &qk_sh[rl][0][0];
    const float* qk1 = &qk_sh[rl][1][0];
    float s0 = 0.f, s1 = 0.f;
    #pragma unroll
    for (int j = 0; j < 16; ++j) {
      int i = d0 + j;
      s0 += a[j]*qk0[i] + t[j]*qk0[128+i] + e[j]*qk0[256+i];
      s1 += a[j]*qk1[i] + t[j]*qk1[128+i] + e[j]*qk1[256+i];
    }
    s0 += __shfl_xor(s0, 1); s0 += __shfl_xor(s0, 2); s0 += __shfl_xor(s0, 4);
    s1 += __shfl_xor(s1, 1); s1 += __shfl_xor(s1, 2); s1 += __shfl_xor(s1, 4);
    if (sub == 0) { s_sh[rl][0][m] = s0; s_sh[rl][1][m] = s1; }
  }
  __syncthreads();

  // ---------- phase D: masked softmax ----------
  if (tid < 16) {
    int rl = tid >> 1, h = tid & 1;
    unsigned mb = mb_sh[rl];
    float sq = sqb_sh[rl][h];
    float s[KN];
    float mx = -3.0e38f;
    #pragma unroll
    for (int m = 0; m < KN; ++m) {
      float v = ((mb >> m) & 1u) ? -1e9f : (s_sh[rl][h][m] + sq) * 0.08838834764831845f;
      s[m] = v; mx = fmaxf(mx, v);
    }
    float sum = 0.f;
    #pragma unroll
    for (int m = 0; m < KN; ++m) { s[m] = expf(s[m] - mx); sum += s[m]; }
    float inv = 1.f / sum;
    #pragma unroll
    for (int m = 0; m < KN; ++m) aw_sh[rl][h][m] = s[m] * inv;
  }
  __syncthreads();

  // ---------- phase E: ctx[r][h] = sum_m attn * k_in (seg-pure waves) ----------
  #pragma unroll
  for (int it = 0; it < 2; ++it) {
    int slot = it*256 + tid;
    if (slot < 384) {
      int seg = slot >> 7;            // 0: nbr feats, 1: time enc, 2: edge feats
      int rem = slot & 127;
      int rl = rem >> 4;
      int d0 = (rem & 15) * 8;
      float c0[8], c1[8];
      #pragma unroll
      for (int e2 = 0; e2 < 8; ++e2) { c0[e2] = 0.f; c1[e2] = 0.f; }
      for (int m = 0; m < KN; ++m) {
        float a0 = aw_sh[rl][0][m], a1 = aw_sh[rl][1][m];
        float v[8];
        if (seg == 0) {
          int nd_ = nd_sh[rl][m];
          if (L == 0) {
            float4 x0 = *(const float4*)(mem + (size_t)nd_*DF + d0);
            float4 x1 = *(const float4*)(mem + (size_t)nd_*DF + d0 + 4);
            float4 y0 = *(const float4*)(nf  + (size_t)nd_*DF + d0);
            float4 y1 = *(const float4*)(nf  + (size_t)nd_*DF + d0 + 4);
            v[0]=x0.x+y0.x; v[1]=x0.y+y0.y; v[2]=x0.z+y0.z; v[3]=x0.w+y0.w;
            v[4]=x1.x+y1.x; v[5]=x1.y+y1.y; v[6]=x1.z+y1.z; v[7]=x1.w+y1.w;
          } else {
            float4 x0 = *(const float4*)(g_out1 + (size_t)nd_*DF + d0);
            float4 x1 = *(const float4*)(g_out1 + (size_t)nd_*DF + d0 + 4);
            v[0]=x0.x; v[1]=x0.y; v[2]=x0.z; v[3]=x0.w;
            v[4]=x1.x; v[5]=x1.y; v[6]=x1.z; v[7]=x1.w;
          }
        } else if (seg == 1) {
          float dtv = dt_sh[rl][m];
          #pragma unroll
          for (int e2 = 0; e2 < 8; ++e2) v[e2] = cosf(dtv*tw_sh[d0+e2] + tb_sh[d0+e2]);
        } else {
          int ei_ = ei_sh[rl][m];
          float4 x0 = *(const float4*)(ef + (size_t)ei_*DF + d0);
          float4 x1 = *(const float4*)(ef + (size_t)ei_*DF + d0 + 4);
          v[0]=x0.x; v[1]=x0.y; v[2]=x0.z; v[3]=x0.w;
          v[4]=x1.x; v[5]=x1.y; v[6]=x1.z; v[7]=x1.w;
        }
        #pragma unroll
        for (int e2 = 0; e2 < 8; ++e2) { c0[e2] += a0*v[e2]; c1[e2] += a1*v[e2]; }
      }
      #pragma unroll
      for (int e2 = 0; e2 < 8; ++e2) {
        qk_sh[rl][0][seg*128 + d0 + e2] = c0[e2];
        qk_sh[rl][1][seg*128 + d0 + e2] = c1[e2];
      }
    }
  }
  __syncthreads();

  // ---------- phase F: o = ctx @ Wv + bv (thread = out col) ----------
  {
    int h = tid >> 7;
    float accv[8];
    float bvc = bv[L*DQ + tid];
    #pragma unroll
    for (int rl = 0; rl < 8; ++rl) accv[rl] = bvc;
    #pragma unroll 4
    for (int i = 0; i < DKI; ++i) {
      float w = wv[(size_t)i*DQ + tid];
      #pragma unroll
      for (int rl = 0; rl < 8; ++rl) accv[rl] += qk_sh[rl][h][i] * w;
    }
    #pragma unroll
    for (int rl = 0; rl < 8; ++rl) q_sh[rl][tid] = accv[rl];   // q dead; o -> q_sh
  }
  __syncthreads();

  // ---------- phase G: Wo + all-masked zero (oo -> qk_sh region) ----------
  {
    float og[8];
    float boc = bo[L*DQ + tid];
    #pragma unroll
    for (int rl = 0; rl < 8; ++rl) og[rl] = boc;
    #pragma unroll 4
    for (int c = 0; c < DQ; ++c) {
      float w = wo[c*DQ + tid];
      #pragma unroll
      for (int rl = 0; rl < 8; ++rl) og[rl] += q_sh[rl][c] * w;
    }
    float* oo = (float*)qk_sh;   // [8][256] region, ctx consumed
    #pragma unroll
    for (int rl = 0; rl < 8; ++rl) oo[rl*DQ + tid] = allm_sh[rl] ? 0.f : og[rl];
  }
  __syncthreads();

  // ---------- phase H: fc1 + relu ----------
  {
    int col = tid & 127, part = tid >> 7;
    const float* oo = (const float*)qk_sh;
    float hv[8];
    #pragma unroll
    for (int rl = 0; rl < 8; ++rl) hv[rl] = 0.f;
    if (part == 0) {
      #pragma unroll 4
      for (int c = 0; c < 192; ++c) {
        float w = f1w[c*DF + col];
        #pragma unroll
        for (int rl = 0; rl < 8; ++rl) hv[rl] += oo[rl*DQ + c] * w;
      }
    } else {
      #pragma unroll 4
      for (int c = 192; c < 256; ++c) {
        float w = f1w[c*DF + col];
        #pragma unroll
        for (int rl = 0; rl < 8; ++rl) hv[rl] += oo[rl*DQ + c] * w;
      }
      #pragma unroll 4
      for (int d = 0; d < DF; ++d) {
        float w = f1w[(DQ + d)*DF + col];
        #pragma unroll
        for (int rl = 0; rl < 8; ++rl) hv[rl] += sf_sh[rl][d] * w;
      }
    }
    if (part == 0) {
      #pragma unroll
      for (int rl = 0; rl < 8; ++rl) h1_sh[rl][col] = hv[rl];
    }
    __syncthreads();
    if (part == 1) {
      float b = fc1b[L*DF + col];
      #pragma unroll
      for (int rl = 0; rl < 8; ++rl)
        h1_sh[rl][col] = fmaxf(h1_sh[rl][col] + hv[rl] + b, 0.f);
    }
  }
  __syncthreads();

  // ---------- phase I: fc2 + write (partials via sf_sh, now dead) ----------
  {
    int col = tid & 127, part = tid >> 7;
    float ov[8];
    #pragma unroll
    for (int rl = 0; rl < 8; ++rl) ov[rl] = 0.f;
    #pragma unroll 4
    for (int i = 0; i < 64; ++i) {
      int c = part*64 + i;
      float w = f2w[c*DF + col];
      #pragma unroll
      for (int rl = 0; rl < 8; ++rl) ov[rl] += h1_sh[rl][c] * w;
    }
    if (part == 0) {
      #pragma unroll
      for (int rl = 0; rl < 8; ++rl) sf_sh[rl][col] = ov[rl];
    }
    __syncthreads();
    if (part == 1) {
      float b = fc2b[L*DF + col];
      #pragma unroll
      for (int rl = 0; rl < 8; ++rl) {
        float res = sf_sh[rl][col] + ov[rl] + b;
        int r = b0 + rl;
        if (L == 0) g_out1[(size_t)r*DF + col] = res;
        else        outf[(size_t)r*DF + col] = res;
      }
    }
  }
}

extern "C" void kernel_launch(void* const* d_in, const int* in_sizes, int n_in,
                              void* d_out, int out_size, void* d_ws, size_t ws_size,
                              hipStream_t stream) {
  (void)in_sizes; (void)n_in; (void)out_size; (void)ws_size; (void)d_ws;
  const float* nf   = (const float*)d_in[0];
  const float* ef   = (const float*)d_in[1];
  const float* mem  = (const float*)d_in[2];
  const float* tsv  = (const float*)d_in[3];
  const float* ets  = (const float*)d_in[4];
  const float* etn  = (const float*)d_in[5];
  const float* tw   = (const float*)d_in[6];
  const float* tb   = (const float*)d_in[7];
  const float* Wq   = (const float*)d_in[8];
  const float* bq   = (const float*)d_in[9];
  const float* Wk   = (const float*)d_in[10];
  const float* bk   = (const float*)d_in[11];
  const float* Wv   = (const float*)d_in[12];
  const float* bv   = (const float*)d_in[13];
  const float* Wo   = (const float*)d_in[14];
  const float* bo   = (const float*)d_in[15];
  const float* f1w  = (const float*)d_in[16];
  const float* f1b  = (const float*)d_in[17];
  const float* f2w  = (const float*)d_in[18];
  const float* f2b  = (const float*)d_in[19];
  const int* srcn   = (const int*)d_in[20];
  const int* nbs    = (const int*)d_in[21];
  const int* eis    = (const int*)d_in[22];
  const int* nbn    = (const int*)d_in[23];
  const int* ein    = (const int*)d_in[24];

  float* out = (float*)d_out;

  hipLaunchKernelGGL(k_wkt, dim3(768), dim3(256), 0, stream, Wk);
  hipLaunchKernelGGL((k_fused<0>), dim3(NR1/8), dim3(256), 0, stream,
      nf, ef, mem, tsv, ets, etn, tw, tb, Wq, bq, bk, Wv, bv, Wo, bo,
      f1w, f1b, f2w, f2b, srcn, nbs, eis, nbn, ein, (float*)nullptr);
  hipLaunchKernelGGL((k_fused<1>), dim3(NB/8), dim3(256), 0, stream,
      nf, ef, mem, tsv, ets, etn, tw, tb, Wq, bq, bk, Wv, bv, Wo, bo,
      f1w, f1b, f2w, f2b, srcn, nbs, eis, nbn, ein, out);
}

// Round 7
// 997.081 us; speedup vs baseline: 7.2445x; 1.3816x over previous
//
#include <hip/hip_runtime.h>
#include <hip/hip_bf16.h>

#define NB   2048
#define KN   20
#define DF   128
#define DQ   256
#define DKI  384
#define NR1  43008
#define SCALE 0.08838834764831845f

typedef short s16x8 __attribute__((ext_vector_type(8)));
typedef short s16x4 __attribute__((ext_vector_type(4)));
typedef float f32x4 __attribute__((ext_vector_type(4)));

// ---------------- static device scratch ----------------
__device__ __hip_bfloat16 g_S   [(size_t)NR1*256];   // [sf | cte] bf16
__device__ __hip_bfloat16 g_QKH [(size_t)NR1*768];
__device__ __hip_bfloat16 g_CTX [(size_t)NR1*768];
__device__ __hip_bfloat16 g_Ob  [(size_t)NR1*256];
__device__ __hip_bfloat16 g_FC1A[(size_t)NR1*384];   // [oo | sf]
__device__ __hip_bfloat16 g_Hb  [(size_t)NR1*128];
__device__ float          g_out1[(size_t)NR1*DF];
__device__ float          g_Wqk [2*256*768];
__device__ float          g_bqk [2*768];
__device__ unsigned char  g_allm[NR1];
__device__ __hip_bfloat16 g_Bqk[2*196608];  // K=256,N=768 tiled
__device__ __hip_bfloat16 g_Bv [2*196608];  // K=768,N=256 block-diag tiled
__device__ __hip_bfloat16 g_Bo [2*65536];   // K=256,N=256
__device__ __hip_bfloat16 g_B1 [2*49152];   // K=384,N=128
__device__ __hip_bfloat16 g_B2 [2*16384];   // K=128,N=128

__device__ __forceinline__ short f2bf(float v) {
  union { __hip_bfloat16 h; short s; } u; u.h = __float2bfloat16(v); return u.s;
}
__device__ __forceinline__ s16x4 pack4(float x, float y, float z, float w) {
  s16x4 o; o[0]=f2bf(x); o[1]=f2bf(y); o[2]=f2bf(z); o[3]=f2bf(w); return o;
}

// ---------------- Wqk = Wq_h @ Wk_h^T fold (per L,h) ----------------
__global__ __launch_bounds__(256)
void k_wqk(const float* __restrict__ Wq, const float* __restrict__ Wk,
           const float* __restrict__ bq) {
  int idx = blockIdx.x*256 + threadIdx.x;          // 2*256*768 = 393216
  int L = idx / 196608, rem = idx % 196608;
  int n = rem >> 8, co = rem & 255;
  int h = n / 384, i = n - h*384;
  const float* wqp = Wq + (size_t)L*DQ*DQ  + (size_t)co*DQ + h*128;
  const float* wkp = Wk + (size_t)L*DKI*DQ + (size_t)i*DQ  + h*128;
  float acc = 0.f;
  #pragma unroll 4
  for (int c = 0; c < 128; ++c) acc += wqp[c]*wkp[c];
  g_Wqk[(size_t)(L*256 + co)*768 + n] = acc;
  if (co == 0) {
    const float* bqp = bq + L*DQ + h*128;
    float b = 0.f;
    for (int c = 0; c < 128; ++c) b += bqp[c]*wkp[c];
    g_bqk[L*768 + n] = b;
  }
}

// ---------------- generic B-tiler: f32 [K][ldsrc] -> tiled bf16 ----------------
__global__ __launch_bounds__(256)
void k_btile(const float* __restrict__ src, int ldsrc, int K, int N,
             __hip_bfloat16* __restrict__ dst, int blkdiag) {
  int slot = blockIdx.x*256 + threadIdx.x;
  if (slot >= (K*N)/8) return;
  int cl = slot & 15, t = slot >> 4;
  int kgn = K >> 3;
  int kg = t % kgn, nt = t / kgn;
  int n = nt*16 + cl;
  s16x8 o;
  #pragma unroll
  for (int e = 0; e < 8; ++e) {
    int k = kg*8 + e; float v;
    if (blkdiag) { int hk = k / 384; v = (hk == (n >> 7)) ? src[(size_t)(k - hk*384)*ldsrc + n] : 0.f; }
    else v = src[(size_t)k*ldsrc + n];
    o[e] = f2bf(v);
  }
  *(s16x8*)(dst + (size_t)slot*8) = o;
}

// ---------------- prep: S = [sf|cte] bf16, FC1A[:,256:384] = sf ----------------
template<int L>
__global__ __launch_bounds__(256)
void k_prep(const float* __restrict__ nf, const float* __restrict__ mem,
            const float* __restrict__ tb,
            const int* __restrict__ srcn, const int* __restrict__ nbs) {
  const int tid = threadIdx.x;
  const int rl = tid >> 5, q = tid & 31, d0 = q*4;
  const int r = blockIdx.x*8 + rl;
  float ax, ay, az, aw;
  if (L == 0) {
    int node = (r < NB) ? srcn[r] : nbs[r - NB];
    float4 x = *(const float4*)(mem + (size_t)node*DF + d0);
    float4 y = *(const float4*)(nf  + (size_t)node*DF + d0);
    ax=x.x+y.x; ay=x.y+y.y; az=x.z+y.z; aw=x.w+y.w;
  } else {
    float4 x = *(const float4*)(g_out1 + (size_t)r*DF + d0);
    ax=x.x; ay=x.y; az=x.z; aw=x.w;
  }
  *(s16x4*)(g_S + (size_t)r*256 + d0) = pack4(ax, ay, az, aw);
  *(s16x4*)(g_S + (size_t)r*256 + 128 + d0) =
      pack4(cosf(tb[d0]), cosf(tb[d0+1]), cosf(tb[d0+2]), cosf(tb[d0+3]));
  *(s16x4*)(g_FC1A + (size_t)r*384 + 256 + d0) = pack4(ax, ay, az, aw);
}

// ---------------- edge kernel: gather + scores + softmax + ctx ----------------
template<int L>
__global__ __launch_bounds__(256)
void k_edge(const float* __restrict__ nf, const float* __restrict__ ef,
            const float* __restrict__ mem, const float* __restrict__ tsv,
            const float* __restrict__ ets, const float* __restrict__ etn,
            const float* __restrict__ tw,  const float* __restrict__ tb,
            const int* __restrict__ nbs, const int* __restrict__ eis,
            const int* __restrict__ nbn, const int* __restrict__ ein,
            const __hip_bfloat16* __restrict__ QKH,
            __hip_bfloat16* __restrict__ CTX)
{
  const int r = blockIdx.x, tid = threadIdx.x;
  __shared__ float kin[KN][388];
  __shared__ float qkh[768];
  __shared__ float tww[DF], tbb[DF];
  __shared__ int   nd[KN], ei[KN];
  __shared__ float dts[KN];
  __shared__ float s_sh[2][KN], aw[2][KN];
  __shared__ unsigned mbits_sh;

  int raw_ = 1;
  if (tid < KN) {
    int nd_, ei_; float dt_;
    if (L == 0) {
      if (r < NB) { raw_ = nbs[r*KN+tid]; nd_ = raw_; ei_ = eis[r*KN+tid]; dt_ = tsv[r] - ets[r*KN+tid]; }
      else { int mm = (r-NB)*KN + tid; raw_ = nbn[mm]; nd_ = raw_; ei_ = ein[mm]; dt_ = tsv[(r-NB)/KN] - etn[mm]; }
    } else {
      raw_ = nbs[r*KN+tid]; nd_ = NB + r*KN + tid; ei_ = eis[r*KN+tid]; dt_ = tsv[r] - ets[r*KN+tid];
    }
    nd[tid] = nd_; ei[tid] = ei_; dts[tid] = dt_;
  }
  if (tid < 64) {
    unsigned long long bal = __ballot(tid < KN && raw_ == 0);
    if (tid == 0) {
      unsigned mb = (unsigned)(bal & 0xFFFFFull);
      mbits_sh = mb;
      g_allm[r] = (mb == 0xFFFFFu) ? 1 : 0;
    }
  }
  if (tid < 96) {
    s16x8 v = *(const s16x8*)(QKH + (size_t)r*768 + tid*8);
    #pragma unroll
    for (int e = 0; e < 8; ++e) {
      union { unsigned u; float f; } x; x.u = ((unsigned)(unsigned short)v[e]) << 16;
      qkh[tid*8 + e] = x.f;
    }
  }
  if (tid < DF) { tww[tid] = tw[tid]; tbb[tid] = tb[tid]; }
  __syncthreads();

  // gather k_in (single pass)
  #pragma unroll
  for (int it = 0; it < 8; ++it) {
    int slot = it*256 + tid;
    if (slot < 1920) {
      int m = slot / 96, p = slot % 96;
      int seg = p >> 5, d0 = (p & 31) * 4;
      float vx, vy, vz, vw;
      if (seg == 0) {
        if (L == 0) {
          float4 a = *(const float4*)(mem + (size_t)nd[m]*DF + d0);
          float4 b = *(const float4*)(nf  + (size_t)nd[m]*DF + d0);
          vx=a.x+b.x; vy=a.y+b.y; vz=a.z+b.z; vw=a.w+b.w;
        } else {
          float4 a = *(const float4*)(g_out1 + (size_t)nd[m]*DF + d0);
          vx=a.x; vy=a.y; vz=a.z; vw=a.w;
        }
      } else if (seg == 1) {
        float dt_ = dts[m];
        vx = cosf(dt_*tww[d0+0] + tbb[d0+0]);
        vy = cosf(dt_*tww[d0+1] + tbb[d0+1]);
        vz = cosf(dt_*tww[d0+2] + tbb[d0+2]);
        vw = cosf(dt_*tww[d0+3] + tbb[d0+3]);
      } else {
        float4 a = *(const float4*)(ef + (size_t)ei[m]*DF + d0);
        vx=a.x; vy=a.y; vz=a.z; vw=a.w;
      }
      float4 o; o.x=vx; o.y=vy; o.z=vz; o.w=vw;
      *(float4*)(&kin[m][seg*128 + d0]) = o;
    }
  }
  __syncthreads();

  // scores: 8 lanes per edge
  if (tid < 160) {
    int m = tid >> 3, sub = tid & 7;
    int i0 = sub * 48;
    float s0 = 0.f, s1 = 0.f;
    #pragma unroll
    for (int j = 0; j < 48; j += 4) {
      float4 kv = *(const float4*)(&kin[m][i0+j]);
      float4 q0 = *(const float4*)(&qkh[i0+j]);
      float4 q1 = *(const float4*)(&qkh[384+i0+j]);
      s0 += kv.x*q0.x + kv.y*q0.y + kv.z*q0.z + kv.w*q0.w;
      s1 += kv.x*q1.x + kv.y*q1.y + kv.z*q1.z + kv.w*q1.w;
    }
    s0 += __shfl_xor(s0, 1); s0 += __shfl_xor(s0, 2); s0 += __shfl_xor(s0, 4);
    s1 += __shfl_xor(s1, 1); s1 += __shfl_xor(s1, 2); s1 += __shfl_xor(s1, 4);
    if (sub == 0) { s_sh[0][m] = s0; s_sh[1][m] = s1; }
  }
  __syncthreads();

  // masked softmax
  if (tid < 2) {
    const int h = tid;
    unsigned mb = mbits_sh;
    float s[KN], mx = -3.0e38f;
    #pragma unroll
    for (int m = 0; m < KN; ++m) {
      float v = ((mb >> m) & 1u) ? -1e9f : s_sh[h][m] * SCALE;
      s[m] = v; mx = fmaxf(mx, v);
    }
    float sum = 0.f;
    #pragma unroll
    for (int m = 0; m < KN; ++m) { s[m] = expf(s[m]-mx); sum += s[m]; }
    float inv = 1.f / sum;
    #pragma unroll
    for (int m = 0; m < KN; ++m) aw[h][m] = s[m]*inv;
  }
  __syncthreads();

  // ctx
  #pragma unroll
  for (int it = 0; it < 3; ++it) {
    int o = it*256 + tid;
    int h = o / 384, i = o - h*384;
    float acc = 0.f;
    #pragma unroll
    for (int m = 0; m < KN; ++m) acc += aw[h][m] * kin[m][i];
    CTX[(size_t)r*768 + o] = __float2bfloat16(acc);
  }
}

// ---------------- generic MFMA GEMM: C[M,N] = A(row-major bf16) @ B(tiled) ----------------
template<int KT, bool F32OUT, bool RELU, bool MASK>
__global__ __launch_bounds__(256, 2)
void k_gemm(const __hip_bfloat16* __restrict__ A, int lda,
            const __hip_bfloat16* __restrict__ B, int kgtot, int nblk,
            void* __restrict__ Cout, int ldc,
            const float* __restrict__ bias,
            const unsigned char* __restrict__ mask)
{
  __shared__ __hip_bfloat16 As[2][128*40];
  __shared__ __hip_bfloat16 Bs[2][128*32];
  const int tid  = threadIdx.x;
  const int lane = tid & 63, wid = tid >> 6;
  const int wm = wid >> 1, wn = wid & 1;
  const int rl = lane & 15, kgs = lane >> 4;
  const int bm = blockIdx.x / nblk, bn = blockIdx.x % nblk;

  f32x4 acc[4][4];
  #pragma unroll
  for (int i = 0; i < 4; ++i)
    #pragma unroll
    for (int j = 0; j < 4; ++j) acc[i][j] = (f32x4){0.f,0.f,0.f,0.f};

  #define STAGE(T, BUF) {                                                      \
    _Pragma("unroll")                                                          \
    for (int i_ = 0; i_ < 2; ++i_) {                                           \
      int row_ = i_*64 + (tid >> 2), kc_ = (tid & 3)*8;                        \
      s16x8 v_ = *(const s16x8*)(A + (size_t)(bm*128 + row_)*lda + (T)*32 + kc_); \
      *(s16x8*)(&As[BUF][row_*40 + kc_]) = v_;                                 \
    }                                                                          \
    _Pragma("unroll")                                                          \
    for (int i_ = 0; i_ < 2; ++i_) {                                           \
      int slot_ = i_*256 + tid;                                                \
      int nt_ = slot_ >> 6, kg_ = (slot_ >> 4) & 3, cl_ = slot_ & 15;          \
      s16x8 w_ = *(const s16x8*)(B + ((size_t)(bn*8 + nt_)*kgtot + (T)*4 + kg_)*128 + cl_*8); \
      *(s16x8*)(&Bs[BUF][slot_*8]) = w_;                                       \
    } }

  STAGE(0, 0);
  __syncthreads();
  int buf = 0;
  for (int t = 0; t < KT; ++t) {
    if (t < KT-1) STAGE(t+1, buf ^ 1);
    s16x8 af[4], bfm[4];
    #pragma unroll
    for (int mtl = 0; mtl < 4; ++mtl)
      af[mtl] = *(const s16x8*)(&As[buf][(wm*64 + mtl*16 + rl)*40 + kgs*8]);
    #pragma unroll
    for (int ntl = 0; ntl < 4; ++ntl)
      bfm[ntl] = *(const s16x8*)(&Bs[buf][((wn*4 + ntl)*4 + kgs)*128 + rl*8]);
    #pragma unroll
    for (int mtl = 0; mtl < 4; ++mtl)
      #pragma unroll
      for (int ntl = 0; ntl < 4; ++ntl)
        acc[mtl][ntl] = __builtin_amdgcn_mfma_f32_16x16x32_bf16(af[mtl], bfm[ntl], acc[mtl][ntl], 0, 0, 0);
    __syncthreads();
    buf ^= 1;
  }
  #undef STAGE

  #pragma unroll
  for (int mtl = 0; mtl < 4; ++mtl) {
    #pragma unroll
    for (int ntl = 0; ntl < 4; ++ntl) {
      int gcol = bn*128 + wn*64 + ntl*16 + rl;
      float bb = bias ? bias[gcol] : 0.f;
      #pragma unroll
      for (int rg = 0; rg < 4; ++rg) {
        int grow = bm*128 + wm*64 + mtl*16 + kgs*4 + rg;
        float v = acc[mtl][ntl][rg] + bb;
        if (RELU) v = fmaxf(v, 0.f);
        if (MASK) { if (mask[grow]) v = 0.f; }
        if (F32OUT) ((float*)Cout)[(size_t)grow*ldc + gcol] = v;
        else ((__hip_bfloat16*)Cout)[(size_t)grow*ldc + gcol] = __float2bfloat16(v);
      }
    }
  }
}

// ---------------- host ----------------
extern "C" void kernel_launch(void* const* d_in, const int* in_sizes, int n_in,
                              void* d_out, int out_size, void* d_ws, size_t ws_size,
                              hipStream_t stream) {
  (void)in_sizes; (void)n_in; (void)out_size; (void)ws_size; (void)d_ws;
  const float* nf   = (const float*)d_in[0];
  const float* ef   = (const float*)d_in[1];
  const float* mem  = (const float*)d_in[2];
  const float* tsv  = (const float*)d_in[3];
  const float* ets  = (const float*)d_in[4];
  const float* etn  = (const float*)d_in[5];
  const float* tw   = (const float*)d_in[6];
  const float* tb   = (const float*)d_in[7];
  const float* Wq   = (const float*)d_in[8];
  const float* bq   = (const float*)d_in[9];
  const float* Wk   = (const float*)d_in[10];
  const float* bv   = (const float*)d_in[13];
  const float* Wv   = (const float*)d_in[12];
  const float* Wo   = (const float*)d_in[14];
  const float* bo   = (const float*)d_in[15];
  const float* f1w  = (const float*)d_in[16];
  const float* f1b  = (const float*)d_in[17];
  const float* f2w  = (const float*)d_in[18];
  const float* f2b  = (const float*)d_in[19];
  const int* srcn   = (const int*)d_in[20];
  const int* nbs    = (const int*)d_in[21];
  const int* eis    = (const int*)d_in[22];
  const int* nbn    = (const int*)d_in[23];
  const int* ein    = (const int*)d_in[24];
  float* out = (float*)d_out;

  __hip_bfloat16 *S, *QKH, *CTX, *Ob, *FC1A, *Hb, *Bqk, *Bv, *Bo, *B1, *B2;
  float *Wqkf, *bqkf, *out1f;
  unsigned char* allm;
  hipGetSymbolAddress((void**)&S,    HIP_SYMBOL(g_S));
  hipGetSymbolAddress((void**)&QKH,  HIP_SYMBOL(g_QKH));
  hipGetSymbolAddress((void**)&CTX,  HIP_SYMBOL(g_CTX));
  hipGetSymbolAddress((void**)&Ob,   HIP_SYMBOL(g_Ob));
  hipGetSymbolAddress((void**)&FC1A, HIP_SYMBOL(g_FC1A));
  hipGetSymbolAddress((void**)&Hb,   HIP_SYMBOL(g_Hb));
  hipGetSymbolAddress((void**)&Bqk,  HIP_SYMBOL(g_Bqk));
  hipGetSymbolAddress((void**)&Bv,   HIP_SYMBOL(g_Bv));
  hipGetSymbolAddress((void**)&Bo,   HIP_SYMBOL(g_Bo));
  hipGetSymbolAddress((void**)&B1,   HIP_SYMBOL(g_B1));
  hipGetSymbolAddress((void**)&B2,   HIP_SYMBOL(g_B2));
  hipGetSymbolAddress((void**)&Wqkf, HIP_SYMBOL(g_Wqk));
  hipGetSymbolAddress((void**)&bqkf, HIP_SYMBOL(g_bqk));
  hipGetSymbolAddress((void**)&out1f,HIP_SYMBOL(g_out1));
  hipGetSymbolAddress((void**)&allm, HIP_SYMBOL(g_allm));

  // weight prep
  hipLaunchKernelGGL(k_wqk, dim3(1536), dim3(256), 0, stream, Wq, Wk, bq);
  for (int L = 0; L < 2; ++L) {
    hipLaunchKernelGGL(k_btile, dim3(96),  dim3(256), 0, stream, Wqkf + (size_t)L*256*768, 768, 256, 768, Bqk + (size_t)L*196608, 0);
    hipLaunchKernelGGL(k_btile, dim3(96),  dim3(256), 0, stream, Wv + (size_t)L*DKI*DQ,    256, 768, 256, Bv  + (size_t)L*196608, 1);
    hipLaunchKernelGGL(k_btile, dim3(32),  dim3(256), 0, stream, Wo + (size_t)L*DQ*DQ,     256, 256, 256, Bo  + (size_t)L*65536,  0);
    hipLaunchKernelGGL(k_btile, dim3(24),  dim3(256), 0, stream, f1w + (size_t)L*384*128,  128, 384, 128, B1  + (size_t)L*49152,  0);
    hipLaunchKernelGGL(k_btile, dim3(8),   dim3(256), 0, stream, f2w + (size_t)L*128*128,  128, 128, 128, B2  + (size_t)L*16384,  0);
  }

  // ---- layer 0 (R = 43008) ----
  {
    const int R = NR1, BMg = R/128;
    hipLaunchKernelGGL((k_prep<0>), dim3(R/8), dim3(256), 0, stream, nf, mem, tb, srcn, nbs);
    hipLaunchKernelGGL((k_gemm<8,false,false,false>), dim3(BMg*6), dim3(256), 0, stream,
        S, 256, Bqk, 32, 6, QKH, 768, bqkf, (const unsigned char*)nullptr);
    hipLaunchKernelGGL((k_edge<0>), dim3(R), dim3(256), 0, stream,
        nf, ef, mem, tsv, ets, etn, tw, tb, nbs, eis, nbn, ein, QKH, CTX);
    hipLaunchKernelGGL((k_gemm<24,false,false,false>), dim3(BMg*2), dim3(256), 0, stream,
        CTX, 768, Bv, 96, 2, Ob, 256, bv, (const unsigned char*)nullptr);
    hipLaunchKernelGGL((k_gemm<8,false,false,true>), dim3(BMg*2), dim3(256), 0, stream,
        Ob, 256, Bo, 32, 2, FC1A, 384, bo, allm);
    hipLaunchKernelGGL((k_gemm<12,false,true,false>), dim3(BMg), dim3(256), 0, stream,
        FC1A, 384, B1, 48, 1, Hb, 128, f1b, (const unsigned char*)nullptr);
    hipLaunchKernelGGL((k_gemm<4,true,false,false>), dim3(BMg), dim3(256), 0, stream,
        Hb, 128, B2, 16, 1, out1f, 128, f2b, (const unsigned char*)nullptr);
  }
  // ---- layer 1 (R = 2048) ----
  {
    const int R = NB, BMg = R/128;
    hipLaunchKernelGGL((k_prep<1>), dim3(R/8), dim3(256), 0, stream, nf, mem, tb, srcn, nbs);
    hipLaunchKernelGGL((k_gemm<8,false,false,false>), dim3(BMg*6), dim3(256), 0, stream,
        S, 256, Bqk + 196608, 32, 6, QKH, 768, bqkf + 768, (const unsigned char*)nullptr);
    hipLaunchKernelGGL((k_edge<1>), dim3(R), dim3(256), 0, stream,
        nf, ef, mem, tsv, ets, etn, tw, tb, nbs, eis, nbn, ein, QKH, CTX);
    hipLaunchKernelGGL((k_gemm<24,false,false,false>), dim3(BMg*2), dim3(256), 0, stream,
        CTX, 768, Bv + 196608, 96, 2, Ob, 256, bv + 256, (const unsigned char*)nullptr);
    hipLaunchKernelGGL((k_gemm<8,false,false,true>), dim3(BMg*2), dim3(256), 0, stream,
        Ob, 256, Bo + 65536, 32, 2, FC1A, 384, bo + 256, allm);
    hipLaunchKernelGGL((k_gemm<12,false,true,false>), dim3(BMg), dim3(256), 0, stream,
        FC1A, 384, B1 + 49152, 48, 1, Hb, 128, f1b + 128, (const unsigned char*)nullptr);
    hipLaunchKernelGGL((k_gemm<4,true,false,false>), dim3(BMg), dim3(256), 0, stream,
        Hb, 128, B2 + 16384, 16, 1, out, 128, f2b + 128, (const unsigned char*)nullptr);
  }
}

// Round 8
// 635.231 us; speedup vs baseline: 11.3712x; 1.5696x over previous
//
#include <hip/hip_runtime.h>
#include <hip/hip_bf16.h>

#define NB   2048
#define KN   20
#define DF   128
#define DQ   256
#define DKI  384
#define NR1  43008
#define SCALE 0.08838834764831845f

typedef short s16x8 __attribute__((ext_vector_type(8)));
typedef short s16x4 __attribute__((ext_vector_type(4)));
typedef float f32x4 __attribute__((ext_vector_type(4)));

// ---------------- static device scratch ----------------
__device__ __hip_bfloat16 g_S   [(size_t)NR1*256];   // [sf | cte] bf16
__device__ __hip_bfloat16 g_QKH [(size_t)NR1*768];
__device__ __hip_bfloat16 g_CTX [(size_t)NR1*768];
__device__ __hip_bfloat16 g_Ob  [(size_t)NR1*256];
__device__ __hip_bfloat16 g_FC1A[(size_t)NR1*384];   // [oo | sf]
__device__ __hip_bfloat16 g_Hb  [(size_t)NR1*128];
__device__ float          g_out1[(size_t)NR1*DF];
__device__ float          g_Wqk [2*256*768];
__device__ float          g_bqk [2*768];
__device__ unsigned char  g_allm[NR1];
__device__ __hip_bfloat16 g_Bqk[2*196608];  // K=256,N=768 tiled
__device__ __hip_bfloat16 g_Bv [2*196608];  // K=768,N=256 block-diag tiled
__device__ __hip_bfloat16 g_Bo [2*65536];   // K=256,N=256
__device__ __hip_bfloat16 g_B1 [2*49152];   // K=384,N=128
__device__ __hip_bfloat16 g_B2 [2*16384];   // K=128,N=128

__device__ __forceinline__ short f2bf(float v) {
  union { __hip_bfloat16 h; short s; } u; u.h = __float2bfloat16(v); return u.s;
}
__device__ __forceinline__ float bf2f(__hip_bfloat16 h) {
  union { __hip_bfloat16 h2[2]; unsigned u; float f; } x;
  x.u = 0; x.h2[1] = h; return x.f;
}
__device__ __forceinline__ s16x4 pack4(float x, float y, float z, float w) {
  s16x4 o; o[0]=f2bf(x); o[1]=f2bf(y); o[2]=f2bf(z); o[3]=f2bf(w); return o;
}

// ---------------- Wqk = Wq_h @ Wk_h^T fold (per L,h) ----------------
__global__ __launch_bounds__(256)
void k_wqk(const float* __restrict__ Wq, const float* __restrict__ Wk,
           const float* __restrict__ bq) {
  int idx = blockIdx.x*256 + threadIdx.x;          // 2*256*768 = 393216
  int L = idx / 196608, rem = idx % 196608;
  int n = rem >> 8, co = rem & 255;
  int h = n / 384, i = n - h*384;
  const float* wqp = Wq + (size_t)L*DQ*DQ  + (size_t)co*DQ + h*128;
  const float* wkp = Wk + (size_t)L*DKI*DQ + (size_t)i*DQ  + h*128;
  float acc = 0.f;
  #pragma unroll 4
  for (int c = 0; c < 128; ++c) acc += wqp[c]*wkp[c];
  g_Wqk[(size_t)(L*256 + co)*768 + n] = acc;
  if (co == 0) {
    const float* bqp = bq + L*DQ + h*128;
    float b = 0.f;
    for (int c = 0; c < 128; ++c) b += bqp[c]*wkp[c];
    g_bqk[L*768 + n] = b;
  }
}

// ---------------- generic B-tiler: f32 [K][ldsrc] -> tiled bf16 ----------------
__global__ __launch_bounds__(256)
void k_btile(const float* __restrict__ src, int ldsrc, int K, int N,
             __hip_bfloat16* __restrict__ dst, int blkdiag) {
  int slot = blockIdx.x*256 + threadIdx.x;
  if (slot >= (K*N)/8) return;
  int cl = slot & 15, t = slot >> 4;
  int kgn = K >> 3;
  int kg = t % kgn, nt = t / kgn;
  int n = nt*16 + cl;
  s16x8 o;
  #pragma unroll
  for (int e = 0; e < 8; ++e) {
    int k = kg*8 + e; float v;
    if (blkdiag) { int hk = k / 384; v = (hk == (n >> 7)) ? src[(size_t)(k - hk*384)*ldsrc + n] : 0.f; }
    else v = src[(size_t)k*ldsrc + n];
    o[e] = f2bf(v);
  }
  *(s16x8*)(dst + (size_t)slot*8) = o;
}

// ---------------- prep: S = [sf|cte] bf16, FC1A[:,256:384] = sf ----------------
template<int L>
__global__ __launch_bounds__(256)
void k_prep(const float* __restrict__ nf, const float* __restrict__ mem,
            const float* __restrict__ tb,
            const int* __restrict__ srcn, const int* __restrict__ nbs) {
  const int tid = threadIdx.x;
  const int rl = tid >> 5, q = tid & 31, d0 = q*4;
  const int r = blockIdx.x*8 + rl;
  float ax, ay, az, aw;
  if (L == 0) {
    int node = (r < NB) ? srcn[r] : nbs[r - NB];
    float4 x = *(const float4*)(mem + (size_t)node*DF + d0);
    float4 y = *(const float4*)(nf  + (size_t)node*DF + d0);
    ax=x.x+y.x; ay=x.y+y.y; az=x.z+y.z; aw=x.w+y.w;
  } else {
    float4 x = *(const float4*)(g_out1 + (size_t)r*DF + d0);
    ax=x.x; ay=x.y; az=x.z; aw=x.w;
  }
  *(s16x4*)(g_S + (size_t)r*256 + d0) = pack4(ax, ay, az, aw);
  *(s16x4*)(g_S + (size_t)r*256 + 128 + d0) =
      pack4(cosf(tb[d0]), cosf(tb[d0+1]), cosf(tb[d0+2]), cosf(tb[d0+3]));
  *(s16x4*)(g_FC1A + (size_t)r*384 + 256 + d0) = pack4(ax, ay, az, aw);
}

// ---------------- edge kernel v2: register-resident gather/scores/ctx ----------------
// wave w owns edges w*5..w*5+4; lane owns dims d = 64*j + lane, j=0..5
// j=0,1 -> node feats; j=2,3 -> time enc; j=4,5 -> edge feats
template<int L>
__global__ __launch_bounds__(256)
void k_edge(const float* __restrict__ nf, const float* __restrict__ ef,
            const float* __restrict__ mem, const float* __restrict__ tsv,
            const float* __restrict__ ets, const float* __restrict__ etn,
            const float* __restrict__ tw,  const float* __restrict__ tb,
            const int* __restrict__ nbs, const int* __restrict__ eis,
            const int* __restrict__ nbn, const int* __restrict__ ein,
            const __hip_bfloat16* __restrict__ QKH,
            __hip_bfloat16* __restrict__ CTX)
{
  const int r = blockIdx.x, tid = threadIdx.x;
  const int lane = tid & 63, w = tid >> 6;

  __shared__ int   nd[KN], ei[KN];
  __shared__ float dts[KN];
  __shared__ float s_sh[2][KN];
  __shared__ float aw_sh[2][KN];
  __shared__ float ctxp[4][768];
  __shared__ unsigned mbits_sh;

  // ---- metadata ----
  int raw_ = 1;
  if (tid < KN) {
    int nd_, ei_; float dt_;
    if (L == 0) {
      if (r < NB) { raw_ = nbs[r*KN+tid]; nd_ = raw_; ei_ = eis[r*KN+tid]; dt_ = tsv[r] - ets[r*KN+tid]; }
      else { int mm = (r-NB)*KN + tid; raw_ = nbn[mm]; nd_ = raw_; ei_ = ein[mm]; dt_ = tsv[(r-NB)/KN] - etn[mm]; }
    } else {
      raw_ = nbs[r*KN+tid]; nd_ = NB + r*KN + tid; ei_ = eis[r*KN+tid]; dt_ = tsv[r] - ets[r*KN+tid];
    }
    nd[tid] = nd_; ei[tid] = ei_; dts[tid] = dt_;
  }
  if (tid < 64) {
    unsigned long long bal = __ballot(tid < KN && raw_ == 0);
    if (tid == 0) {
      unsigned mb = (unsigned)(bal & 0xFFFFFull);
      mbits_sh = mb;
      g_allm[r] = (mb == 0xFFFFFu) ? 1 : 0;
    }
  }

  // ---- per-lane constants (registers, loaded once) ----
  float q0[6], q1[6];
  #pragma unroll
  for (int j = 0; j < 6; ++j) {
    q0[j] = bf2f(QKH[(size_t)r*768 +       j*64 + lane]);
    q1[j] = bf2f(QKH[(size_t)r*768 + 384 + j*64 + lane]);
  }
  float twr0 = tw[lane],      twr1 = tw[64 + lane];
  float tbr0 = tb[lane],      tbr1 = tb[64 + lane];
  __syncthreads();

  // ---- gather + scores (values stay in registers) ----
  float ve[5][6];
  #pragma unroll
  for (int e = 0; e < 5; ++e) {
    const int m = w*5 + e;
    const int nd_ = nd[m], ei_ = ei[m];
    const float dt_ = dts[m];
    float v0, v1;
    if (L == 0) {
      v0 = mem[(size_t)nd_*DF +      lane] + nf[(size_t)nd_*DF +      lane];
      v1 = mem[(size_t)nd_*DF + 64 + lane] + nf[(size_t)nd_*DF + 64 + lane];
    } else {
      v0 = g_out1[(size_t)nd_*DF +      lane];
      v1 = g_out1[(size_t)nd_*DF + 64 + lane];
    }
    float v2 = __cosf(dt_*twr0 + tbr0);
    float v3 = __cosf(dt_*twr1 + tbr1);
    float v4 = ef[(size_t)ei_*DF +      lane];
    float v5 = ef[(size_t)ei_*DF + 64 + lane];
    ve[e][0]=v0; ve[e][1]=v1; ve[e][2]=v2; ve[e][3]=v3; ve[e][4]=v4; ve[e][5]=v5;
    float p0 = v0*q0[0] + v1*q0[1] + v2*q0[2] + v3*q0[3] + v4*q0[4] + v5*q0[5];
    float p1 = v0*q1[0] + v1*q1[1] + v2*q1[2] + v3*q1[3] + v4*q1[4] + v5*q1[5];
    #pragma unroll
    for (int off = 1; off < 64; off <<= 1) {
      p0 += __shfl_xor(p0, off);
      p1 += __shfl_xor(p1, off);
    }
    if (lane == 0) { s_sh[0][m] = p0; s_sh[1][m] = p1; }
  }
  __syncthreads();

  // ---- wave-parallel masked softmax: lanes [0,32)=head0, [32,64)=head1 ----
  if (tid < 64) {
    const int h = tid >> 5, mm = tid & 31;
    const unsigned mb = mbits_sh;
    float sc;
    if (mm < KN) sc = ((mb >> mm) & 1u) ? -1e9f : s_sh[h][mm] * SCALE;
    else         sc = -3.0e38f;
    float mx = sc;
    #pragma unroll
    for (int off = 1; off < 32; off <<= 1) mx = fmaxf(mx, __shfl_xor(mx, off));
    float ev = (mm < KN) ? __expf(sc - mx) : 0.f;
    float sum = ev;
    #pragma unroll
    for (int off = 1; off < 32; off <<= 1) sum += __shfl_xor(sum, off);
    if (mm < KN) aw_sh[h][mm] = ev / sum;
  }
  __syncthreads();

  // ---- ctx: weighted sum of register-resident values ----
  {
    float c0[6] = {0,0,0,0,0,0}, c1[6] = {0,0,0,0,0,0};
    #pragma unroll
    for (int e = 0; e < 5; ++e) {
      const int m = w*5 + e;
      const float a0 = aw_sh[0][m], a1 = aw_sh[1][m];
      #pragma unroll
      for (int j = 0; j < 6; ++j) {
        c0[j] += a0 * ve[e][j];
        c1[j] += a1 * ve[e][j];
      }
    }
    #pragma unroll
    for (int j = 0; j < 6; ++j) {
      ctxp[w][      j*64 + lane] = c0[j];
      ctxp[w][384 + j*64 + lane] = c1[j];
    }
  }
  __syncthreads();

  // ---- combine wave partials, write CTX (bf16) ----
  #pragma unroll
  for (int it = 0; it < 3; ++it) {
    int o = it*256 + tid;
    float s = ctxp[0][o] + ctxp[1][o] + ctxp[2][o] + ctxp[3][o];
    CTX[(size_t)r*768 + o] = __float2bfloat16(s);
  }
}

// ---------------- generic MFMA GEMM: C[M,N] = A(row-major bf16) @ B(tiled) ----------------
template<int KT, bool F32OUT, bool RELU, bool MASK>
__global__ __launch_bounds__(256, 2)
void k_gemm(const __hip_bfloat16* __restrict__ A, int lda,
            const __hip_bfloat16* __restrict__ B, int kgtot, int nblk,
            void* __restrict__ Cout, int ldc,
            const float* __restrict__ bias,
            const unsigned char* __restrict__ mask)
{
  __shared__ __hip_bfloat16 As[2][128*40];
  __shared__ __hip_bfloat16 Bs[2][128*32];
  const int tid  = threadIdx.x;
  const int lane = tid & 63, wid = tid >> 6;
  const int wm = wid >> 1, wn = wid & 1;
  const int rl = lane & 15, kgs = lane >> 4;
  const int bm = blockIdx.x / nblk, bn = blockIdx.x % nblk;

  f32x4 acc[4][4];
  #pragma unroll
  for (int i = 0; i < 4; ++i)
    #pragma unroll
    for (int j = 0; j < 4; ++j) acc[i][j] = (f32x4){0.f,0.f,0.f,0.f};

  #define STAGE(T, BUF) {                                                      \
    _Pragma("unroll")                                                          \
    for (int i_ = 0; i_ < 2; ++i_) {                                           \
      int row_ = i_*64 + (tid >> 2), kc_ = (tid & 3)*8;                        \
      s16x8 v_ = *(const s16x8*)(A + (size_t)(bm*128 + row_)*lda + (T)*32 + kc_); \
      *(s16x8*)(&As[BUF][row_*40 + kc_]) = v_;                                 \
    }                                                                          \
    _Pragma("unroll")                                                          \
    for (int i_ = 0; i_ < 2; ++i_) {                                           \
      int slot_ = i_*256 + tid;                                                \
      int nt_ = slot_ >> 6, kg_ = (slot_ >> 4) & 3, cl_ = slot_ & 15;          \
      s16x8 w_ = *(const s16x8*)(B + ((size_t)(bn*8 + nt_)*kgtot + (T)*4 + kg_)*128 + cl_*8); \
      *(s16x8*)(&Bs[BUF][slot_*8]) = w_;                                       \
    } }

  STAGE(0, 0);
  __syncthreads();
  int buf = 0;
  for (int t = 0; t < KT; ++t) {
    if (t < KT-1) STAGE(t+1, buf ^ 1);
    s16x8 af[4], bfm[4];
    #pragma unroll
    for (int mtl = 0; mtl < 4; ++mtl)
      af[mtl] = *(const s16x8*)(&As[buf][(wm*64 + mtl*16 + rl)*40 + kgs*8]);
    #pragma unroll
    for (int ntl = 0; ntl < 4; ++ntl)
      bfm[ntl] = *(const s16x8*)(&Bs[buf][((wn*4 + ntl)*4 + kgs)*128 + rl*8]);
    #pragma unroll
    for (int mtl = 0; mtl < 4; ++mtl)
      #pragma unroll
      for (int ntl = 0; ntl < 4; ++ntl)
        acc[mtl][ntl] = __builtin_amdgcn_mfma_f32_16x16x32_bf16(af[mtl], bfm[ntl], acc[mtl][ntl], 0, 0, 0);
    __syncthreads();
    buf ^= 1;
  }
  #undef STAGE

  #pragma unroll
  for (int mtl = 0; mtl < 4; ++mtl) {
    #pragma unroll
    for (int ntl = 0; ntl < 4; ++ntl) {
      int gcol = bn*128 + wn*64 + ntl*16 + rl;
      float bb = bias ? bias[gcol] : 0.f;
      #pragma unroll
      for (int rg = 0; rg < 4; ++rg) {
        int grow = bm*128 + wm*64 + mtl*16 + kgs*4 + rg;
        float v = acc[mtl][ntl][rg] + bb;
        if (RELU) v = fmaxf(v, 0.f);
        if (MASK) { if (mask[grow]) v = 0.f; }
        if (F32OUT) ((float*)Cout)[(size_t)grow*ldc + gcol] = v;
        else ((__hip_bfloat16*)Cout)[(size_t)grow*ldc + gcol] = __float2bfloat16(v);
      }
    }
  }
}

// ---------------- host ----------------
extern "C" void kernel_launch(void* const* d_in, const int* in_sizes, int n_in,
                              void* d_out, int out_size, void* d_ws, size_t ws_size,
                              hipStream_t stream) {
  (void)in_sizes; (void)n_in; (void)out_size; (void)ws_size; (void)d_ws;
  const float* nf   = (const float*)d_in[0];
  const float* ef   = (const float*)d_in[1];
  const float* mem  = (const float*)d_in[2];
  const float* tsv  = (const float*)d_in[3];
  const float* ets  = (const float*)d_in[4];
  const float* etn  = (const float*)d_in[5];
  const float* tw   = (const float*)d_in[6];
  const float* tb   = (const float*)d_in[7];
  const float* Wq   = (const float*)d_in[8];
  const float* bq   = (const float*)d_in[9];
  const float* Wk   = (const float*)d_in[10];
  const float* bv   = (const float*)d_in[13];
  const float* Wv   = (const float*)d_in[12];
  const float* Wo   = (const float*)d_in[14];
  const float* bo   = (const float*)d_in[15];
  const float* f1w  = (const float*)d_in[16];
  const float* f1b  = (const float*)d_in[17];
  const float* f2w  = (const float*)d_in[18];
  const float* f2b  = (const float*)d_in[19];
  const int* srcn   = (const int*)d_in[20];
  const int* nbs    = (const int*)d_in[21];
  const int* eis    = (const int*)d_in[22];
  const int* nbn    = (const int*)d_in[23];
  const int* ein    = (const int*)d_in[24];
  float* out = (float*)d_out;

  __hip_bfloat16 *S, *QKH, *CTX, *Ob, *FC1A, *Hb, *Bqk, *Bv, *Bo, *B1, *B2;
  float *Wqkf, *bqkf, *out1f;
  unsigned char* allm;
  hipGetSymbolAddress((void**)&S,    HIP_SYMBOL(g_S));
  hipGetSymbolAddress((void**)&QKH,  HIP_SYMBOL(g_QKH));
  hipGetSymbolAddress((void**)&CTX,  HIP_SYMBOL(g_CTX));
  hipGetSymbolAddress((void**)&Ob,   HIP_SYMBOL(g_Ob));
  hipGetSymbolAddress((void**)&FC1A, HIP_SYMBOL(g_FC1A));
  hipGetSymbolAddress((void**)&Hb,   HIP_SYMBOL(g_Hb));
  hipGetSymbolAddress((void**)&Bqk,  HIP_SYMBOL(g_Bqk));
  hipGetSymbolAddress((void**)&Bv,   HIP_SYMBOL(g_Bv));
  hipGetSymbolAddress((void**)&Bo,   HIP_SYMBOL(g_Bo));
  hipGetSymbolAddress((void**)&B1,   HIP_SYMBOL(g_B1));
  hipGetSymbolAddress((void**)&B2,   HIP_SYMBOL(g_B2));
  hipGetSymbolAddress((void**)&Wqkf, HIP_SYMBOL(g_Wqk));
  hipGetSymbolAddress((void**)&bqkf, HIP_SYMBOL(g_bqk));
  hipGetSymbolAddress((void**)&out1f,HIP_SYMBOL(g_out1));
  hipGetSymbolAddress((void**)&allm, HIP_SYMBOL(g_allm));

  // weight prep
  hipLaunchKernelGGL(k_wqk, dim3(1536), dim3(256), 0, stream, Wq, Wk, bq);
  for (int L = 0; L < 2; ++L) {
    hipLaunchKernelGGL(k_btile, dim3(96),  dim3(256), 0, stream, Wqkf + (size_t)L*256*768, 768, 256, 768, Bqk + (size_t)L*196608, 0);
    hipLaunchKernelGGL(k_btile, dim3(96),  dim3(256), 0, stream, Wv + (size_t)L*DKI*DQ,    256, 768, 256, Bv  + (size_t)L*196608, 1);
    hipLaunchKernelGGL(k_btile, dim3(32),  dim3(256), 0, stream, Wo + (size_t)L*DQ*DQ,     256, 256, 256, Bo  + (size_t)L*65536,  0);
    hipLaunchKernelGGL(k_btile, dim3(24),  dim3(256), 0, stream, f1w + (size_t)L*384*128,  128, 384, 128, B1  + (size_t)L*49152,  0);
    hipLaunchKernelGGL(k_btile, dim3(8),   dim3(256), 0, stream, f2w + (size_t)L*128*128,  128, 128, 128, B2  + (size_t)L*16384,  0);
  }

  // ---- layer 0 (R = 43008) ----
  {
    const int R = NR1, BMg = R/128;
    hipLaunchKernelGGL((k_prep<0>), dim3(R/8), dim3(256), 0, stream, nf, mem, tb, srcn, nbs);
    hipLaunchKernelGGL((k_gemm<8,false,false,false>), dim3(BMg*6), dim3(256), 0, stream,
        S, 256, Bqk, 32, 6, QKH, 768, bqkf, (const unsigned char*)nullptr);
    hipLaunchKernelGGL((k_edge<0>), dim3(R), dim3(256), 0, stream,
        nf, ef, mem, tsv, ets, etn, tw, tb, nbs, eis, nbn, ein, QKH, CTX);
    hipLaunchKernelGGL((k_gemm<24,false,false,false>), dim3(BMg*2), dim3(256), 0, stream,
        CTX, 768, Bv, 96, 2, Ob, 256, bv, (const unsigned char*)nullptr);
    hipLaunchKernelGGL((k_gemm<8,false,false,true>), dim3(BMg*2), dim3(256), 0, stream,
        Ob, 256, Bo, 32, 2, FC1A, 384, bo, allm);
    hipLaunchKernelGGL((k_gemm<12,false,true,false>), dim3(BMg), dim3(256), 0, stream,
        FC1A, 384, B1, 48, 1, Hb, 128, f1b, (const unsigned char*)nullptr);
    hipLaunchKernelGGL((k_gemm<4,true,false,false>), dim3(BMg), dim3(256), 0, stream,
        Hb, 128, B2, 16, 1, out1f, 128, f2b, (const unsigned char*)nullptr);
  }
  // ---- layer 1 (R = 2048) ----
  {
    const int R = NB, BMg = R/128;
    hipLaunchKernelGGL((k_prep<1>), dim3(R/8), dim3(256), 0, stream, nf, mem, tb, srcn, nbs);
    hipLaunchKernelGGL((k_gemm<8,false,false,false>), dim3(BMg*6), dim3(256), 0, stream,
        S, 256, Bqk + 196608, 32, 6, QKH, 768, bqkf + 768, (const unsigned char*)nullptr);
    hipLaunchKernelGGL((k_edge<1>), dim3(R), dim3(256), 0, stream,
        nf, ef, mem, tsv, ets, etn, tw, tb, nbs, eis, nbn, ein, QKH, CTX);
    hipLaunchKernelGGL((k_gemm<24,false,false,false>), dim3(BMg*2), dim3(256), 0, stream,
        CTX, 768, Bv + 196608, 96, 2, Ob, 256, bv + 256, (const unsigned char*)nullptr);
    hipLaunchKernelGGL((k_gemm<8,false,false,true>), dim3(BMg*2), dim3(256), 0, stream,
        Ob, 256, Bo + 65536, 32, 2, FC1A, 384, bo + 256, allm);
    hipLaunchKernelGGL((k_gemm<12,false,true,false>), dim3(BMg), dim3(256), 0, stream,
        FC1A, 384, B1 + 49152, 48, 1, Hb, 128, f1b + 128, (const unsigned char*)nullptr);
    hipLaunchKernelGGL((k_gemm<4,true,false,false>), dim3(BMg), dim3(256), 0, stream,
        Hb, 128, B2 + 16384, 16, 1, out, 128, f2b + 128, (const unsigned char*)nullptr);
  }
}

// Round 9
// 611.240 us; speedup vs baseline: 11.8175x; 1.0392x over previous
//
#include <hip/hip_runtime.h>
#include <hip/hip_bf16.h>

#define NB   2048
#define KN   20
#define DF   128
#define DQ   256
#define DKI  384
#define NR1  43008
#define SCALE 0.08838834764831845f

typedef short s16x8 __attribute__((ext_vector_type(8)));
typedef short s16x4 __attribute__((ext_vector_type(4)));
typedef float f32x4 __attribute__((ext_vector_type(4)));

// ---------------- static device scratch ----------------
__device__ __hip_bfloat16 g_S   [(size_t)NR1*256];   // [sf | cte] bf16
__device__ __hip_bfloat16 g_QKH [(size_t)NR1*768];
__device__ __hip_bfloat16 g_CTX [(size_t)NR1*768];   // [ctx_h0 | ctx_h1]
__device__ __hip_bfloat16 g_Ob  [(size_t)NR1*256];
__device__ __hip_bfloat16 g_FC1A[(size_t)NR1*384];   // [oo | sf]
__device__ __hip_bfloat16 g_Hb  [(size_t)NR1*128];
__device__ float          g_out1[(size_t)NR1*DF];
__device__ float          g_Wqk [2*256*768];
__device__ float          g_bqk [2*768];
__device__ unsigned char  g_allm[NR1];
__device__ __hip_bfloat16 g_Bqk[2*196608];  // K=256,N=768 tiled
__device__ __hip_bfloat16 g_Bv [4*49152];   // per (L,h): K=384,N=128 tiled
__device__ __hip_bfloat16 g_Bo [2*65536];   // K=256,N=256
__device__ __hip_bfloat16 g_B1 [2*49152];   // K=384,N=128
__device__ __hip_bfloat16 g_B2 [2*16384];   // K=128,N=128

__device__ __forceinline__ short f2bf(float v) {
  union { __hip_bfloat16 h; short s; } u; u.h = __float2bfloat16(v); return u.s;
}
__device__ __forceinline__ float2 bfpair(unsigned u) {
  union { unsigned u2; float f; } a, b;
  a.u2 = u << 16;          // low bf16
  b.u2 = u & 0xFFFF0000u;  // high bf16
  float2 r; r.x = a.f; r.y = b.f; return r;
}
__device__ __forceinline__ s16x4 pack4(float x, float y, float z, float w) {
  s16x4 o; o[0]=f2bf(x); o[1]=f2bf(y); o[2]=f2bf(z); o[3]=f2bf(w); return o;
}

// ---------------- Wqk = Wq_h @ Wk_h^T fold (per L,h) ----------------
__global__ __launch_bounds__(256)
void k_wqk(const float* __restrict__ Wq, const float* __restrict__ Wk,
           const float* __restrict__ bq) {
  int idx = blockIdx.x*256 + threadIdx.x;          // 2*256*768 = 393216
  int L = idx / 196608, rem = idx % 196608;
  int n = rem >> 8, co = rem & 255;
  int h = n / 384, i = n - h*384;
  const float* wqp = Wq + (size_t)L*DQ*DQ  + (size_t)co*DQ + h*128;
  const float* wkp = Wk + (size_t)L*DKI*DQ + (size_t)i*DQ  + h*128;
  float acc = 0.f;
  #pragma unroll 4
  for (int c = 0; c < 128; ++c) acc += wqp[c]*wkp[c];
  g_Wqk[(size_t)(L*256 + co)*768 + n] = acc;
  if (co == 0) {
    const float* bqp = bq + L*DQ + h*128;
    float b = 0.f;
    for (int c = 0; c < 128; ++c) b += bqp[c]*wkp[c];
    g_bqk[L*768 + n] = b;
  }
}

// ---------------- generic B-tiler: f32 [K][ldsrc] -> tiled bf16 ----------------
__global__ __launch_bounds__(256)
void k_btile(const float* __restrict__ src, int ldsrc, int K, int N,
             __hip_bfloat16* __restrict__ dst) {
  int slot = blockIdx.x*256 + threadIdx.x;
  if (slot >= (K*N)/8) return;
  int cl = slot & 15, t = slot >> 4;
  int kgn = K >> 3;
  int kg = t % kgn, nt = t / kgn;
  int n = nt*16 + cl;
  s16x8 o;
  #pragma unroll
  for (int e = 0; e < 8; ++e) o[e] = f2bf(src[(size_t)(kg*8 + e)*ldsrc + n]);
  *(s16x8*)(dst + (size_t)slot*8) = o;
}

// ---------------- prep: S = [sf|cte] bf16, FC1A[:,256:384] = sf ----------------
template<int L>
__global__ __launch_bounds__(256)
void k_prep(const float* __restrict__ nf, const float* __restrict__ mem,
            const float* __restrict__ tb,
            const int* __restrict__ srcn, const int* __restrict__ nbs) {
  const int tid = threadIdx.x;
  const int rl = tid >> 5, q = tid & 31, d0 = q*4;
  const int r = blockIdx.x*8 + rl;
  float ax, ay, az, aw;
  if (L == 0) {
    int node = (r < NB) ? srcn[r] : nbs[r - NB];
    float4 x = *(const float4*)(mem + (size_t)node*DF + d0);
    float4 y = *(const float4*)(nf  + (size_t)node*DF + d0);
    ax=x.x+y.x; ay=x.y+y.y; az=x.z+y.z; aw=x.w+y.w;
  } else {
    float4 x = *(const float4*)(g_out1 + (size_t)r*DF + d0);
    ax=x.x; ay=x.y; az=x.z; aw=x.w;
  }
  *(s16x4*)(g_S + (size_t)r*256 + d0) = pack4(ax, ay, az, aw);
  *(s16x4*)(g_S + (size_t)r*256 + 128 + d0) =
      pack4(cosf(tb[d0]), cosf(tb[d0+1]), cosf(tb[d0+2]), cosf(tb[d0+3]));
  *(s16x4*)(g_FC1A + (size_t)r*384 + 256 + d0) = pack4(ax, ay, az, aw);
}

// ---------------- edge kernel v3: float2 lanes + deep load pipelining ----------------
// wave w owns edges w*5..w*5+4; lane owns dims {2*lane, 2*lane+1} of each segment
template<int L>
__global__ __launch_bounds__(256, 6)
void k_edge(const float* __restrict__ nf, const float* __restrict__ ef,
            const float* __restrict__ mem, const float* __restrict__ tsv,
            const float* __restrict__ ets, const float* __restrict__ etn,
            const float* __restrict__ tw,  const float* __restrict__ tb,
            const int* __restrict__ nbs, const int* __restrict__ eis,
            const int* __restrict__ nbn, const int* __restrict__ ein,
            const __hip_bfloat16* __restrict__ QKH,
            __hip_bfloat16* __restrict__ CTX)
{
  const int r = blockIdx.x, tid = threadIdx.x;
  const int lane = tid & 63, w = tid >> 6;

  __shared__ int   nd[KN], ei[KN];
  __shared__ float dts[KN];
  __shared__ float s_sh[2][KN];
  __shared__ float aw_sh[2][KN];
  __shared__ float ctxp[4][768];
  __shared__ unsigned mbits_sh;

  // ---- metadata ----
  int raw_ = 1;
  if (tid < KN) {
    int nd_, ei_; float dt_;
    if (L == 0) {
      if (r < NB) { raw_ = nbs[r*KN+tid]; nd_ = raw_; ei_ = eis[r*KN+tid]; dt_ = tsv[r] - ets[r*KN+tid]; }
      else { int mm = (r-NB)*KN + tid; raw_ = nbn[mm]; nd_ = raw_; ei_ = ein[mm]; dt_ = tsv[(r-NB)/KN] - etn[mm]; }
    } else {
      raw_ = nbs[r*KN+tid]; nd_ = NB + r*KN + tid; ei_ = eis[r*KN+tid]; dt_ = tsv[r] - ets[r*KN+tid];
    }
    nd[tid] = nd_; ei[tid] = ei_; dts[tid] = dt_;
  }
  if (tid < 64) {
    unsigned long long bal = __ballot(tid < KN && raw_ == 0);
    if (tid == 0) {
      unsigned mb = (unsigned)(bal & 0xFFFFFull);
      mbits_sh = mb;
      g_allm[r] = (mb == 0xFFFFFu) ? 1 : 0;
    }
  }

  // ---- per-lane constants (registers): q slices + time-table slice ----
  const __hip_bfloat16* Qr = QKH + (size_t)r*768;
  float2 q0[3], q1[3];
  #pragma unroll
  for (int seg = 0; seg < 3; ++seg) {
    q0[seg] = bfpair(*(const unsigned*)(Qr +       seg*128 + 2*lane));
    q1[seg] = bfpair(*(const unsigned*)(Qr + 384 + seg*128 + 2*lane));
  }
  float2 twr = *(const float2*)(tw + 2*lane);
  float2 tbr = *(const float2*)(tb + 2*lane);
  __syncthreads();

  // ---- issue ALL gather loads first (deep pipeline), then compute ----
  int   nds[5], eir[5]; float dtr[5];
  #pragma unroll
  for (int e = 0; e < 5; ++e) {
    int m = w*5 + e;
    nds[e] = nd[m]; eir[e] = ei[m]; dtr[e] = dts[m];
  }
  float2 vm[5], vf[5], vef[5];
  #pragma unroll
  for (int e = 0; e < 5; ++e) {
    if (L == 0) {
      vm[e] = *(const float2*)(mem + (size_t)nds[e]*DF + 2*lane);
      vf[e] = *(const float2*)(nf  + (size_t)nds[e]*DF + 2*lane);
    } else {
      vm[e] = *(const float2*)(g_out1 + (size_t)nds[e]*DF + 2*lane);
    }
    vef[e] = *(const float2*)(ef + (size_t)eir[e]*DF + 2*lane);
  }

  // ---- per-edge: time enc, score dot, full-wave reduce ----
  float2 vn[5], vt[5];
  #pragma unroll
  for (int e = 0; e < 5; ++e) {
    if (L == 0) { vn[e].x = vm[e].x + vf[e].x; vn[e].y = vm[e].y + vf[e].y; }
    else        vn[e] = vm[e];
    vt[e].x = __cosf(dtr[e]*twr.x + tbr.x);
    vt[e].y = __cosf(dtr[e]*twr.y + tbr.y);
    float p0 = vn[e].x*q0[0].x + vn[e].y*q0[0].y
             + vt[e].x*q0[1].x + vt[e].y*q0[1].y
             + vef[e].x*q0[2].x + vef[e].y*q0[2].y;
    float p1 = vn[e].x*q1[0].x + vn[e].y*q1[0].y
             + vt[e].x*q1[1].x + vt[e].y*q1[1].y
             + vef[e].x*q1[2].x + vef[e].y*q1[2].y;
    #pragma unroll
    for (int off = 1; off < 64; off <<= 1) {
      p0 += __shfl_xor(p0, off);
      p1 += __shfl_xor(p1, off);
    }
    if (lane == 0) { s_sh[0][w*5+e] = p0; s_sh[1][w*5+e] = p1; }
  }
  __syncthreads();

  // ---- wave-parallel masked softmax: lanes [0,32)=head0, [32,64)=head1 ----
  if (tid < 64) {
    const int h = tid >> 5, mm = tid & 31;
    const unsigned mb = mbits_sh;
    float sc;
    if (mm < KN) sc = ((mb >> mm) & 1u) ? -1e9f : s_sh[h][mm] * SCALE;
    else         sc = -3.0e38f;
    float mx = sc;
    #pragma unroll
    for (int off = 1; off < 32; off <<= 1) mx = fmaxf(mx, __shfl_xor(mx, off));
    float ev = (mm < KN) ? __expf(sc - mx) : 0.f;
    float sum = ev;
    #pragma unroll
    for (int off = 1; off < 32; off <<= 1) sum += __shfl_xor(sum, off);
    if (mm < KN) aw_sh[h][mm] = ev / sum;
  }
  __syncthreads();

  // ---- ctx: weighted sums of register-resident values ----
  {
    float2 c0n = {0,0}, c0t = {0,0}, c0e = {0,0};
    float2 c1n = {0,0}, c1t = {0,0}, c1e = {0,0};
    #pragma unroll
    for (int e = 0; e < 5; ++e) {
      const int m = w*5 + e;
      const float a0 = aw_sh[0][m], a1 = aw_sh[1][m];
      c0n.x += a0*vn[e].x;  c0n.y += a0*vn[e].y;
      c0t.x += a0*vt[e].x;  c0t.y += a0*vt[e].y;
      c0e.x += a0*vef[e].x; c0e.y += a0*vef[e].y;
      c1n.x += a1*vn[e].x;  c1n.y += a1*vn[e].y;
      c1t.x += a1*vt[e].x;  c1t.y += a1*vt[e].y;
      c1e.x += a1*vef[e].x; c1e.y += a1*vef[e].y;
    }
    *(float2*)&ctxp[w][      2*lane] = c0n;
    *(float2*)&ctxp[w][128 + 2*lane] = c0t;
    *(float2*)&ctxp[w][256 + 2*lane] = c0e;
    *(float2*)&ctxp[w][384 + 2*lane] = c1n;
    *(float2*)&ctxp[w][512 + 2*lane] = c1t;
    *(float2*)&ctxp[w][640 + 2*lane] = c1e;
  }
  __syncthreads();

  // ---- combine wave partials, write CTX (bf16) ----
  #pragma unroll
  for (int it = 0; it < 3; ++it) {
    int o = it*256 + tid;
    float s = ctxp[0][o] + ctxp[1][o] + ctxp[2][o] + ctxp[3][o];
    CTX[(size_t)r*768 + o] = __float2bfloat16(s);
  }
}

// ---------------- generic MFMA GEMM: C[M,N] = A(row-major bf16) @ B(tiled) ----------------
template<int KT, bool F32OUT, bool RELU, bool MASK>
__global__ __launch_bounds__(256, 2)
void k_gemm(const __hip_bfloat16* __restrict__ A, int lda,
            const __hip_bfloat16* __restrict__ B, int kgtot, int nblk,
            void* __restrict__ Cout, int ldc,
            const float* __restrict__ bias,
            const unsigned char* __restrict__ mask)
{
  __shared__ __hip_bfloat16 As[2][128*40];
  __shared__ __hip_bfloat16 Bs[2][128*32];
  const int tid  = threadIdx.x;
  const int lane = tid & 63, wid = tid >> 6;
  const int wm = wid >> 1, wn = wid & 1;
  const int rl = lane & 15, kgs = lane >> 4;
  const int bm = blockIdx.x / nblk, bn = blockIdx.x % nblk;

  f32x4 acc[4][4];
  #pragma unroll
  for (int i = 0; i < 4; ++i)
    #pragma unroll
    for (int j = 0; j < 4; ++j) acc[i][j] = (f32x4){0.f,0.f,0.f,0.f};

  #define STAGE(T, BUF) {                                                      \
    _Pragma("unroll")                                                          \
    for (int i_ = 0; i_ < 2; ++i_) {                                           \
      int row_ = i_*64 + (tid >> 2), kc_ = (tid & 3)*8;                        \
      s16x8 v_ = *(const s16x8*)(A + (size_t)(bm*128 + row_)*lda + (T)*32 + kc_); \
      *(s16x8*)(&As[BUF][row_*40 + kc_]) = v_;                                 \
    }                                                                          \
    _Pragma("unroll")                                                          \
    for (int i_ = 0; i_ < 2; ++i_) {                                           \
      int slot_ = i_*256 + tid;                                                \
      int nt_ = slot_ >> 6, kg_ = (slot_ >> 4) & 3, cl_ = slot_ & 15;          \
      s16x8 w_ = *(const s16x8*)(B + ((size_t)(bn*8 + nt_)*kgtot + (T)*4 + kg_)*128 + cl_*8); \
      *(s16x8*)(&Bs[BUF][slot_*8]) = w_;                                       \
    } }

  STAGE(0, 0);
  __syncthreads();
  int buf = 0;
  for (int t = 0; t < KT; ++t) {
    if (t < KT-1) STAGE(t+1, buf ^ 1);
    s16x8 af[4], bfm[4];
    #pragma unroll
    for (int mtl = 0; mtl < 4; ++mtl)
      af[mtl] = *(const s16x8*)(&As[buf][(wm*64 + mtl*16 + rl)*40 + kgs*8]);
    #pragma unroll
    for (int ntl = 0; ntl < 4; ++ntl)
      bfm[ntl] = *(const s16x8*)(&Bs[buf][((wn*4 + ntl)*4 + kgs)*128 + rl*8]);
    #pragma unroll
    for (int mtl = 0; mtl < 4; ++mtl)
      #pragma unroll
      for (int ntl = 0; ntl < 4; ++ntl)
        acc[mtl][ntl] = __builtin_amdgcn_mfma_f32_16x16x32_bf16(af[mtl], bfm[ntl], acc[mtl][ntl], 0, 0, 0);
    __syncthreads();
    buf ^= 1;
  }
  #undef STAGE

  #pragma unroll
  for (int mtl = 0; mtl < 4; ++mtl) {
    #pragma unroll
    for (int ntl = 0; ntl < 4; ++ntl) {
      int gcol = bn*128 + wn*64 + ntl*16 + rl;
      float bb = bias ? bias[gcol] : 0.f;
      #pragma unroll
      for (int rg = 0; rg < 4; ++rg) {
        int grow = bm*128 + wm*64 + mtl*16 + kgs*4 + rg;
        float v = acc[mtl][ntl][rg] + bb;
        if (RELU) v = fmaxf(v, 0.f);
        if (MASK) { if (mask[grow]) v = 0.f; }
        if (F32OUT) ((float*)Cout)[(size_t)grow*ldc + gcol] = v;
        else ((__hip_bfloat16*)Cout)[(size_t)grow*ldc + gcol] = __float2bfloat16(v);
      }
    }
  }
}

// ---------------- host ----------------
extern "C" void kernel_launch(void* const* d_in, const int* in_sizes, int n_in,
                              void* d_out, int out_size, void* d_ws, size_t ws_size,
                              hipStream_t stream) {
  (void)in_sizes; (void)n_in; (void)out_size; (void)ws_size; (void)d_ws;
  const float* nf   = (const float*)d_in[0];
  const float* ef   = (const float*)d_in[1];
  const float* mem  = (const float*)d_in[2];
  const float* tsv  = (const float*)d_in[3];
  const float* ets  = (const float*)d_in[4];
  const float* etn  = (const float*)d_in[5];
  const float* tw   = (const float*)d_in[6];
  const float* tb   = (const float*)d_in[7];
  const float* Wq   = (const float*)d_in[8];
  const float* bq   = (const float*)d_in[9];
  const float* Wk   = (const float*)d_in[10];
  const float* bv   = (const float*)d_in[13];
  const float* Wv   = (const float*)d_in[12];
  const float* Wo   = (const float*)d_in[14];
  const float* bo   = (const float*)d_in[15];
  const float* f1w  = (const float*)d_in[16];
  const float* f1b  = (const float*)d_in[17];
  const float* f2w  = (const float*)d_in[18];
  const float* f2b  = (const float*)d_in[19];
  const int* srcn   = (const int*)d_in[20];
  const int* nbs    = (const int*)d_in[21];
  const int* eis    = (const int*)d_in[22];
  const int* nbn    = (const int*)d_in[23];
  const int* ein    = (const int*)d_in[24];
  float* out = (float*)d_out;

  __hip_bfloat16 *S, *QKH, *CTX, *Ob, *FC1A, *Hb, *Bqk, *Bv, *Bo, *B1, *B2;
  float *Wqkf, *bqkf, *out1f;
  unsigned char* allm;
  hipGetSymbolAddress((void**)&S,    HIP_SYMBOL(g_S));
  hipGetSymbolAddress((void**)&QKH,  HIP_SYMBOL(g_QKH));
  hipGetSymbolAddress((void**)&CTX,  HIP_SYMBOL(g_CTX));
  hipGetSymbolAddress((void**)&Ob,   HIP_SYMBOL(g_Ob));
  hipGetSymbolAddress((void**)&FC1A, HIP_SYMBOL(g_FC1A));
  hipGetSymbolAddress((void**)&Hb,   HIP_SYMBOL(g_Hb));
  hipGetSymbolAddress((void**)&Bqk,  HIP_SYMBOL(g_Bqk));
  hipGetSymbolAddress((void**)&Bv,   HIP_SYMBOL(g_Bv));
  hipGetSymbolAddress((void**)&Bo,   HIP_SYMBOL(g_Bo));
  hipGetSymbolAddress((void**)&B1,   HIP_SYMBOL(g_B1));
  hipGetSymbolAddress((void**)&B2,   HIP_SYMBOL(g_B2));
  hipGetSymbolAddress((void**)&Wqkf, HIP_SYMBOL(g_Wqk));
  hipGetSymbolAddress((void**)&bqkf, HIP_SYMBOL(g_bqk));
  hipGetSymbolAddress((void**)&out1f,HIP_SYMBOL(g_out1));
  hipGetSymbolAddress((void**)&allm, HIP_SYMBOL(g_allm));

  // weight prep
  hipLaunchKernelGGL(k_wqk, dim3(1536), dim3(256), 0, stream, Wq, Wk, bq);
  for (int L = 0; L < 2; ++L) {
    hipLaunchKernelGGL(k_btile, dim3(96), dim3(256), 0, stream, Wqkf + (size_t)L*256*768, 768, 256, 768, Bqk + (size_t)L*196608);
    for (int h = 0; h < 2; ++h)
      hipLaunchKernelGGL(k_btile, dim3(24), dim3(256), 0, stream, Wv + (size_t)L*DKI*DQ + h*128, 256, 384, 128, Bv + (size_t)(L*2+h)*49152);
    hipLaunchKernelGGL(k_btile, dim3(32), dim3(256), 0, stream, Wo + (size_t)L*DQ*DQ,    256, 256, 256, Bo + (size_t)L*65536);
    hipLaunchKernelGGL(k_btile, dim3(24), dim3(256), 0, stream, f1w + (size_t)L*384*128, 128, 384, 128, B1 + (size_t)L*49152);
    hipLaunchKernelGGL(k_btile, dim3(8),  dim3(256), 0, stream, f2w + (size_t)L*128*128, 128, 128, 128, B2 + (size_t)L*16384);
  }

  // ---- layer 0 (R = 43008) ----
  {
    const int R = NR1, BMg = R/128;
    hipLaunchKernelGGL((k_prep<0>), dim3(R/8), dim3(256), 0, stream, nf, mem, tb, srcn, nbs);
    hipLaunchKernelGGL((k_gemm<8,false,false,false>), dim3(BMg*6), dim3(256), 0, stream,
        S, 256, Bqk, 32, 6, QKH, 768, bqkf, (const unsigned char*)nullptr);
    hipLaunchKernelGGL((k_edge<0>), dim3(R), dim3(256), 0, stream,
        nf, ef, mem, tsv, ets, etn, tw, tb, nbs, eis, nbn, ein, QKH, CTX);
    for (int h = 0; h < 2; ++h)
      hipLaunchKernelGGL((k_gemm<12,false,false,false>), dim3(BMg), dim3(256), 0, stream,
          CTX + h*384, 768, Bv + (size_t)h*49152, 48, 1, Ob + h*128, 256, bv + h*128, (const unsigned char*)nullptr);
    hipLaunchKernelGGL((k_gemm<8,false,false,true>), dim3(BMg*2), dim3(256), 0, stream,
        Ob, 256, Bo, 32, 2, FC1A, 384, bo, allm);
    hipLaunchKernelGGL((k_gemm<12,false,true,false>), dim3(BMg), dim3(256), 0, stream,
        FC1A, 384, B1, 48, 1, Hb, 128, f1b, (const unsigned char*)nullptr);
    hipLaunchKernelGGL((k_gemm<4,true,false,false>), dim3(BMg), dim3(256), 0, stream,
        Hb, 128, B2, 16, 1, out1f, 128, f2b, (const unsigned char*)nullptr);
  }
  // ---- layer 1 (R = 2048) ----
  {
    const int R = NB, BMg = R/128;
    hipLaunchKernelGGL((k_prep<1>), dim3(R/8), dim3(256), 0, stream, nf, mem, tb, srcn, nbs);
    hipLaunchKernelGGL((k_gemm<8,false,false,false>), dim3(BMg*6), dim3(256), 0, stream,
        S, 256, Bqk + 196608, 32, 6, QKH, 768, bqkf + 768, (const unsigned char*)nullptr);
    hipLaunchKernelGGL((k_edge<1>), dim3(R), dim3(256), 0, stream,
        nf, ef, mem, tsv, ets, etn, tw, tb, nbs, eis, nbn, ein, QKH, CTX);
    for (int h = 0; h < 2; ++h)
      hipLaunchKernelGGL((k_gemm<12,false,false,false>), dim3(BMg), dim3(256), 0, stream,
          CTX + h*384, 768, Bv + (size_t)(2+h)*49152, 48, 1, Ob + h*128, 256, bv + 256 + h*128, (const unsigned char*)nullptr);
    hipLaunchKernelGGL((k_gemm<8,false,false,true>), dim3(BMg*2), dim3(256), 0, stream,
        Ob, 256, Bo + 65536, 32, 2, FC1A, 384, bo + 256, allm);
    hipLaunchKernelGGL((k_gemm<12,false,true,false>), dim3(BMg), dim3(256), 0, stream,
        FC1A, 384, B1 + 49152, 48, 1, Hb, 128, f1b + 128, (const unsigned char*)nullptr);
    hipLaunchKernelGGL((k_gemm<4,true,false,false>), dim3(BMg), dim3(256), 0, stream,
        Hb, 128, B2 + 16384, 16, 1, out, 128, f2b + 128, (const unsigned char*)nullptr);
  }
}